// Round 13
// baseline (574.369 us; speedup 1.0000x reference)
//
#include <hip/hip_runtime.h>
#include <hip/hip_bf16.h>

// GCNEncoder — r28: critical-path cuts. (a) C = A^T Qb gathered in f32:
// applyR also emits Bf1=(float)Qb (same value fin produced); spmmC reads Bf1
// (f64 accum) -> Cm directly; Cd dropped; dinv2 from f32 C (~1e-7 drift).
// (b) repack: K4 = qsum|spmmC32|hw2(h1); K5 = fin-chores|spmm2 (sum->max).
// (c) P-chain spmm 4 segs/block (proven spmmC partition). chol untouched
// (52us structural floor, 4 attempts).
// History: r27 556us; r26 578us; r25 650us; r24 695us; r22 836us; r16 1138us.

#define NN    4096
#define NEDG  131072
#define INC   512
#define HIDC  512
#define OUTC  64
#define RK    64
#define NDOM  4
#define EPSBN 1e-5f

typedef unsigned short ushortT;
typedef __attribute__((ext_vector_type(8))) short bf16x8;
typedef __attribute__((ext_vector_type(4))) float f32x4;

static inline int cdiv(int a, int b){ return (a + b - 1) / b; }

__device__ __forceinline__ float bf2f(unsigned u){ return __uint_as_float(u << 16); }

// ---------------- input dtype detection ----------------
__global__ __launch_bounds__(256) void k_detect(const unsigned short* __restrict__ p,
                                                int* __restrict__ flag){
  int t = threadIdx.x;
  int cnt = 0;
  for (int i = t; i < 4096; i += 256){
    unsigned short v = p[2*i];
    int e = (v >> 7) & 0xFF;
    if (e >= 100 && e <= 140) cnt++;
  }
  __shared__ int sh[256];
  sh[t] = cnt; __syncthreads();
  for (int off = 128; off > 0; off >>= 1){ if (t < off) sh[t] += sh[t+off]; __syncthreads(); }
  if (t == 0) *flag = (sh[0] >= 2048) ? 0 : 1;
}

// ---------------- fused upcast ----------------
__device__ __forceinline__ float upc1(const void* s, int f, int off){
  return f ? ((const float*)s)[off]
           : __bfloat162float(((const __hip_bfloat16*)s)[off]);
}
__device__ __forceinline__ ushortT tobf(float v){
  __hip_bfloat16 h = __float2bfloat16(v);
  return *(ushortT*)&h;
}
#define SEG_X   2097152
#define SEG_W1  262144
#define SEG_W   131072
#define SEG_WMU 32768
#define SEG_GB  2048
#define SEG_B1  512
#define SEG_BO  64
#define OFF1 (SEG_X)
#define OFF2 (OFF1+SEG_W1)
#define OFF3 (OFF2+SEG_W)
#define OFF4 (OFF3+SEG_WMU)
#define OFF5 (OFF4+SEG_WMU)
#define OFF6 (OFF5+SEG_GB)
#define OFF7 (OFF6+SEG_GB)
#define OFF8 (OFF7+SEG_B1)
#define OFF9 (OFF8+SEG_BO)
#define OFFT (OFF9+SEG_BO)

__global__ __launch_bounds__(256) void k_upcast_all(
    const void* x, const void* W1, const void* w, const void* Wmu, const void* Wlv,
    const void* gm, const void* bt, const void* b1, const void* bmu, const void* blv,
    const int* __restrict__ isf32,
    float* dx, float* dW1, float* dw, float* dWmu, float* dWlv,
    float* dgm, float* dbt, float* db1, float* dbmu, float* dblv,
    ushortT* xbf, ushortT* W1bf, ushortT* Wmubf, ushortT* Wlvbf){
  int i = blockIdx.x*256 + threadIdx.x;
  if (i >= OFFT) return;
  int f = *isf32;
  if      (i < OFF1){ float v = upc1(x, f, i); dx[i] = v; xbf[i] = tobf(v); }
  else if (i < OFF2){ float v = upc1(W1, f, i - OFF1); dW1[i - OFF1] = v; W1bf[i - OFF1] = tobf(v); }
  else if (i < OFF3) dw  [i - OFF2] = upc1(w,   f, i - OFF2);
  else if (i < OFF4){ float v = upc1(Wmu, f, i - OFF3); dWmu[i - OFF3] = v; Wmubf[i - OFF3] = tobf(v); }
  else if (i < OFF5){ float v = upc1(Wlv, f, i - OFF4); dWlv[i - OFF4] = v; Wlvbf[i - OFF4] = tobf(v); }
  else if (i < OFF6) dgm [i - OFF5] = upc1(gm,  f, i - OFF5);
  else if (i < OFF7) dbt [i - OFF6] = upc1(bt,  f, i - OFF6);
  else if (i < OFF8) db1 [i - OFF7] = upc1(b1,  f, i - OFF7);
  else if (i < OFF9) dbmu[i - OFF8] = upc1(bmu, f, i - OFF8);
  else               dblv[i - OFF9] = upc1(blv, f, i - OFF9);
}

// ---------------- small utils ----------------
__global__ __launch_bounds__(256) void k_prep(float* deg, int* cntR, int* cntC, int* dcnt,
                                              float* bnsum){
  int i = blockIdx.x*256 + threadIdx.x;
  if (i < NN){ deg[i] = 1.0f; cntR[i] = 0; cntC[i] = 0; }
  if (i < NDOM) dcnt[i] = 0;
  if (i < 8*HIDC) bnsum[i] = 0.f;
}

// ---------------- graph preprocessing ----------------
__global__ __launch_bounds__(256) void k_hist(const int* __restrict__ row, const int* __restrict__ col,
                                              const float* __restrict__ w, float* deg,
                                              int* cntR, int* cntC){
  int e = blockIdx.x*256 + threadIdx.x;
  if (e < NEDG){
    atomicAdd(&deg[col[e]], w[e]);
    atomicAdd(&cntR[row[e]], 1);
    atomicAdd(&cntC[col[e]], 1);
  }
}
__global__ __launch_bounds__(256) void k_dinv(const float* deg, float* dinv, int n){
  int i = blockIdx.x*256 + threadIdx.x;
  if (i < n){ float d = deg[i]; dinv[i] = (d > 0.f) ? 1.f/sqrtf(d) : 0.f; }
}
__global__ __launch_bounds__(256) void k_norm1(const int* __restrict__ row, const int* __restrict__ col,
                                               const float* __restrict__ w, const float* __restrict__ dinv,
                                               float* __restrict__ nrm){
  int e = blockIdx.x*256 + threadIdx.x;
  if (e < NEDG) nrm[e] = dinv[row[e]] * w[e] * dinv[col[e]];
}
__global__ __launch_bounds__(1024) void k_scan4096(const int* __restrict__ cnt,
                                                   int* __restrict__ ptr, int* __restrict__ pos){
  __shared__ int sh[1024];
  int t = threadIdx.x;
  int b = t*4;
  int a0 = cnt[b], a1 = cnt[b+1], a2 = cnt[b+2], a3 = cnt[b+3];
  sh[t] = a0 + a1 + a2 + a3;
  __syncthreads();
  for (int off = 1; off < 1024; off <<= 1){
    int v = (t >= off) ? sh[t-off] : 0;
    __syncthreads();
    sh[t] += v;
    __syncthreads();
  }
  int excl = (t == 0) ? 0 : sh[t-1];
  ptr[b]   = excl;            pos[b]   = excl;
  ptr[b+1] = excl+a0;         pos[b+1] = excl+a0;
  ptr[b+2] = excl+a0+a1;      pos[b+2] = excl+a0+a1;
  ptr[b+3] = excl+a0+a1+a2;   pos[b+3] = excl+a0+a1+a2;
  if (t == 1023) ptr[4096] = sh[1023];
}
__global__ __launch_bounds__(256) void k_scatter(const int* __restrict__ row, const int* __restrict__ col,
                                                 int* posR, int* posC, int* eidR, int* eidC){
  int e = blockIdx.x*256 + threadIdx.x;
  if (e < NEDG){
    int p = atomicAdd(&posR[row[e]], 1); eidR[p] = e;
    int q = atomicAdd(&posC[col[e]], 1); eidC[q] = e;
  }
}
__global__ __launch_bounds__(256) void k_edges(const int* __restrict__ rowA, const int* __restrict__ colA,
        const float* __restrict__ wf, const float* __restrict__ nrm,
        const int* __restrict__ eidR, const int* __restrict__ eidC,
        int* __restrict__ csrSrc, float* __restrict__ csrW,
        int* __restrict__ cscSrc, float* __restrict__ cscW, float* __restrict__ cscN){
  int p = blockIdx.x*256 + threadIdx.x;
  if (p < NEDG){
    int eR = eidR[p]; csrSrc[p] = colA[eR]; csrW[p] = wf[eR];
    int eC = eidC[p]; cscSrc[p] = rowA[eC]; cscW[p] = wf[eC]; cscN[p] = nrm[eC];
  }
}
__global__ __launch_bounds__(256) void k_dcnt(const int* __restrict__ y, int* dcnt){
  int i = blockIdx.x*256 + threadIdx.x;
  if (i < NN) atomicAdd(&dcnt[y[i]], 1);
}

// ---------------- threefry2x32 (KAT-verified) ----------------
__device__ __forceinline__ unsigned rotl32(unsigned x, unsigned d){ return (x << d) | (x >> (32u - d)); }
#define TF_ROUND4(R0,R1,R2,R3) \
  x0 += x1; x1 = rotl32(x1,R0); x1 ^= x0; \
  x0 += x1; x1 = rotl32(x1,R1); x1 ^= x0; \
  x0 += x1; x1 = rotl32(x1,R2); x1 ^= x0; \
  x0 += x1; x1 = rotl32(x1,R3); x1 ^= x0;

__device__ __forceinline__ void tf2x32(unsigned k0, unsigned k1, unsigned c0, unsigned c1,
                                       unsigned* o0, unsigned* o1){
  unsigned ks2 = 0x1BD11BDAu ^ k0 ^ k1;
  unsigned x0 = c0 + k0, x1 = c1 + k1;
  TF_ROUND4(13,15,26,6);   x0 += k1;  x1 += ks2 + 1u;
  TF_ROUND4(17,29,16,24);  x0 += ks2; x1 += k0 + 2u;
  TF_ROUND4(13,15,26,6);   x0 += k0;  x1 += k1 + 3u;
  TF_ROUND4(17,29,16,24);  x0 += k1;  x1 += ks2 + 4u;
  TF_ROUND4(13,15,26,6);   x0 += ks2; x1 += k0 + 5u;
  *o0 = x0; *o1 = x1;
}

// ---------------- omega (verified; f32 out; + Gd zero fold) ----------------
__device__ double erfinv64(double x){
  double w = -log1p(-x*x);
  double p;
  if (w < 5.0){
    w -= 2.5;
    p = 2.81022636e-08;  p = p*w + 3.43273939e-07; p = p*w - 3.5233877e-06;
    p = p*w - 4.39150654e-06; p = p*w + 0.00021858087; p = p*w - 0.00125372503;
    p = p*w - 0.00417768164;  p = p*w + 0.246640727;   p = p*w + 1.50140941;
  } else {
    w = sqrt(w) - 3.0;
    p = -0.000200214257; p = p*w + 0.000100950558; p = p*w + 0.00134934322;
    p = p*w - 0.00367342844; p = p*w + 0.00573950773; p = p*w - 0.0076224613;
    p = p*w + 0.00943887047; p = p*w + 1.00167406;    p = p*w + 2.83297682;
  }
  double y = p * x;
  const double c = 1.1283791670955126;   // 2/sqrt(pi)
  #pragma unroll
  for (int it = 0; it < 3; it++){
    double err = erf(y) - x;
    y -= err / (c * exp(-y*y));
  }
  return y;
}

__device__ float bits_to_normal(unsigned b){
  float f = __uint_as_float((b >> 9) | 0x3f800000u) - 1.0f;
  const float lo = -0.99999994f;
  float x = fmaxf(lo, f * 2.0f + lo);
  double r = 1.4142135623730951 * erfinv64((double)x);
  return (float)r;
}

__global__ __launch_bounds__(256) void k_omega(float* __restrict__ om, double* __restrict__ Gd){
  int i = blockIdx.x*256 + threadIdx.x;
  if (i < RK*RK) Gd[i] = 0.0;
  if (i >= 262144) return;
  unsigned o0, o1;
  tf2x32(0u, 42u, 0u, (unsigned)i, &o0, &o1);
  om[i] = bits_to_normal(o0 ^ o1);
}

// ---------------- bf16 MFMA GEMM (r22-proven) + bf16 C copy ----------------
__global__ __launch_bounds__(256) void k_gemm_bf16(
    const ushortT* __restrict__ A, const ushortT* __restrict__ B,
    float* __restrict__ Cc, ushortT* __restrict__ Cbf){
  __shared__ ushortT As2[64][40];
  __shared__ ushortT Bs2[64][40];
  int t = threadIdx.x;
  int bm = blockIdx.y * 64, bn = blockIdx.x * 64;
  int w = t >> 6, l = t & 63;
  int lr = l & 15, lk = l >> 4;
  f32x4 acc[4] = {};
  int ar = t >> 2, ac = (t & 3) * 8;
  int bc = t & 63, bk = (t >> 6) * 8;
  for (int k0 = 0; k0 < 512; k0 += 32){
    *(uint4*)&As2[ar][ac] = *(const uint4*)&A[(size_t)(bm + ar) * 512 + k0 + ac];
    ushortT tmp[8];
    #pragma unroll
    for (int j = 0; j < 8; j++)
      tmp[j] = B[(size_t)(k0 + bk + j) * 512 + bn + bc];
    *(uint4*)&Bs2[bc][bk] = *(uint4*)tmp;
    __syncthreads();
    bf16x8 afrag = *(bf16x8*)&As2[w * 16 + lr][lk * 8];
    #pragma unroll
    for (int nt = 0; nt < 4; nt++){
      bf16x8 bfrag = *(bf16x8*)&Bs2[nt * 16 + lr][lk * 8];
      acc[nt] = __builtin_amdgcn_mfma_f32_16x16x32_bf16(afrag, bfrag, acc[nt], 0, 0, 0);
    }
    __syncthreads();
  }
  #pragma unroll
  for (int nt = 0; nt < 4; nt++){
    #pragma unroll
    for (int i = 0; i < 4; i++){
      size_t idx = (size_t)(bm + w * 16 + lk * 4 + i) * 512 + bn + nt * 16 + lr;
      float v = acc[nt][i];
      Cc[idx] = v;
      Cbf[idx] = tobf(v);
    }
  }
}

// device body: paired hw GEMM
__device__ __forceinline__ void d_hw2(int bx, int t,
    const ushortT* __restrict__ A, const ushortT* __restrict__ Bm,
    const ushortT* __restrict__ Bl, float* __restrict__ Ca, float* __restrict__ Cb){
  __shared__ ushortT As2[64][40];
  __shared__ ushortT Bs2[64][40];
  int nb = NN/64;
  int second = bx >= nb;
  int bm = (bx - (second ? nb : 0)) * 64;
  const ushortT* B = second ? Bl : Bm;
  float* Cc = second ? Cb : Ca;
  int w = t >> 6, l = t & 63;
  int lr = l & 15, lk = l >> 4;
  f32x4 acc[4] = {};
  int ar = t >> 2, ac = (t & 3) * 8;
  int bc = t & 63, bk = (t >> 6) * 8;
  for (int k0 = 0; k0 < 512; k0 += 32){
    *(uint4*)&As2[ar][ac] = *(const uint4*)&A[(size_t)(bm + ar) * 512 + k0 + ac];
    ushortT tmp[8];
    #pragma unroll
    for (int j = 0; j < 8; j++)
      tmp[j] = B[(size_t)(k0 + bk + j) * 64 + bc];
    *(uint4*)&Bs2[bc][bk] = *(uint4*)tmp;
    __syncthreads();
    bf16x8 afrag = *(bf16x8*)&As2[w * 16 + lr][lk * 8];
    #pragma unroll
    for (int nt = 0; nt < 4; nt++){
      bf16x8 bfrag = *(bf16x8*)&Bs2[nt * 16 + lr][lk * 8];
      acc[nt] = __builtin_amdgcn_mfma_f32_16x16x32_bf16(afrag, bfrag, acc[nt], 0, 0, 0);
    }
    __syncthreads();
  }
  #pragma unroll
  for (int nt = 0; nt < 4; nt++){
    #pragma unroll
    for (int i = 0; i < 4; i++){
      Cc[(size_t)(bm + w * 16 + lk * 4 + i) * 64 + nt * 16 + lr] = acc[nt][i];
    }
  }
}
__global__ __launch_bounds__(256) void k_gemm_hw2(
    const ushortT* __restrict__ A, const ushortT* __restrict__ Bm,
    const ushortT* __restrict__ Bl, float* __restrict__ Ca, float* __restrict__ Cb){
  d_hw2(blockIdx.x, threadIdx.x, A, Bm, Bl, Ca, Cb);
}

// ---------------- GEMM (fp32, h2 dense) ----------------
__global__ __launch_bounds__(256) void k_gemm_nn(int M, int Nn, int K,
      const float* __restrict__ A, int lda, const float* __restrict__ B, int ldb,
      float* __restrict__ Cc, int ldc, const float* __restrict__ rowscale,
      const float* __restrict__ kscale, const float* __restrict__ bias){
  __shared__ float As[16][65];
  __shared__ float Bs[16][65];
  int bm = blockIdx.y*64, bn = blockIdx.x*64;
  int t = threadIdx.x;
  int tr = t >> 4, tc = t & 15;
  float acc[4][4] = {};
  for (int k0 = 0; k0 < K; k0 += 16){
    #pragma unroll
    for (int q = 0; q < 4; q++){
      int idx = t*4 + q;
      int m = idx >> 4, kk = idx & 15;
      As[kk][m] = A[(size_t)(bm+m)*lda + (k0+kk)];
    }
    #pragma unroll
    for (int q = 0; q < 4; q++){
      int idx = t + q*256;
      int kk = idx >> 6, n = idx & 63;
      float ks = kscale ? kscale[k0+kk] : 1.0f;
      Bs[kk][n] = B[(size_t)(k0+kk)*ldb + (bn+n)] * ks;
    }
    __syncthreads();
    #pragma unroll
    for (int kk = 0; kk < 16; kk++){
      float a0 = As[kk][tr*4+0], a1 = As[kk][tr*4+1], a2 = As[kk][tr*4+2], a3 = As[kk][tr*4+3];
      float b0 = Bs[kk][tc*4+0], b1 = Bs[kk][tc*4+1], b2 = Bs[kk][tc*4+2], b3 = Bs[kk][tc*4+3];
      acc[0][0] += a0*b0; acc[0][1] += a0*b1; acc[0][2] += a0*b2; acc[0][3] += a0*b3;
      acc[1][0] += a1*b0; acc[1][1] += a1*b1; acc[1][2] += a1*b2; acc[1][3] += a1*b3;
      acc[2][0] += a2*b0; acc[2][1] += a2*b1; acc[2][2] += a2*b2; acc[2][3] += a2*b3;
      acc[3][0] += a3*b0; acc[3][1] += a3*b1; acc[3][2] += a3*b2; acc[3][3] += a3*b3;
    }
    __syncthreads();
  }
  #pragma unroll
  for (int i2 = 0; i2 < 4; i2++){
    int m = bm + tr*4 + i2;
    float rs = rowscale ? rowscale[m] : 1.0f;
    #pragma unroll
    for (int j2 = 0; j2 < 4; j2++){
      int n = bn + tc*4 + j2;
      float v = acc[i2][j2] * rs;
      if (bias) v += bias[n];
      Cc[(size_t)m*ldc + n] = v;
    }
  }
}

// paired zout2/zout3 GEMMs
__global__ __launch_bounds__(256) void k_gemm_nn2(
      const float* __restrict__ A, const float* __restrict__ Um,
      const float* __restrict__ rowscale,
      const float* __restrict__ bmu, const float* __restrict__ blv,
      float* __restrict__ zout){
  __shared__ float As[16][65];
  __shared__ float Bs[16][65];
  int z = blockIdx.z;
  const float* B = Um + (size_t)z*RK*RK;
  const float* bias = z ? blv : bmu;
  float* Cc = zout + (size_t)(2+z)*NN*OUTC;
  int bm = blockIdx.y*64;
  int t = threadIdx.x;
  int tr = t >> 4, tc = t & 15;
  float acc[4][4] = {};
  for (int k0 = 0; k0 < RK; k0 += 16){
    #pragma unroll
    for (int q = 0; q < 4; q++){
      int idx = t*4 + q;
      int m = idx >> 4, kk = idx & 15;
      As[kk][m] = A[(size_t)(bm+m)*RK + (k0+kk)];
    }
    #pragma unroll
    for (int q = 0; q < 4; q++){
      int idx = t + q*256;
      int kk = idx >> 6, n = idx & 63;
      Bs[kk][n] = B[(size_t)(k0+kk)*RK + n];
    }
    __syncthreads();
    #pragma unroll
    for (int kk = 0; kk < 16; kk++){
      float a0 = As[kk][tr*4+0], a1 = As[kk][tr*4+1], a2 = As[kk][tr*4+2], a3 = As[kk][tr*4+3];
      float b0 = Bs[kk][tc*4+0], b1 = Bs[kk][tc*4+1], b2 = Bs[kk][tc*4+2], b3 = Bs[kk][tc*4+3];
      acc[0][0] += a0*b0; acc[0][1] += a0*b1; acc[0][2] += a0*b2; acc[0][3] += a0*b3;
      acc[1][0] += a1*b0; acc[1][1] += a1*b1; acc[1][2] += a1*b2; acc[1][3] += a1*b3;
      acc[2][0] += a2*b0; acc[2][1] += a2*b1; acc[2][2] += a2*b2; acc[2][3] += a2*b3;
      acc[3][0] += a3*b0; acc[3][1] += a3*b1; acc[3][2] += a3*b2; acc[3][3] += a3*b3;
    }
    __syncthreads();
  }
  #pragma unroll
  for (int i2 = 0; i2 < 4; i2++){
    int m = bm + tr*4 + i2;
    float rs = rowscale[m];
    #pragma unroll
    for (int j2 = 0; j2 < 4; j2++){
      int n = tc*4 + j2;
      Cc[(size_t)m*OUTC + n] = acc[i2][j2] * rs + bias[n];
    }
  }
}

// split-K TN (Tm)
__global__ __launch_bounds__(256) void k_gemm_tn_sk(int M, int Nn, int K, int kchunk,
      const float* __restrict__ A, int lda, const float* __restrict__ B, int ldb,
      float* __restrict__ Cc, int ldc, const float* __restrict__ kscale){
  __shared__ float As[32][17];
  __shared__ float Bs[32][17];
  int bm = blockIdx.y*16, bn = blockIdx.x*16;
  int kb = blockIdx.z*kchunk, ke = kb + kchunk;
  int t = threadIdx.x;
  int tm = t >> 4, tn = t & 15;
  float acc = 0.f;
  for (int k0 = kb; k0 < ke; k0 += 32){
    #pragma unroll
    for (int q = 0; q < 2; q++){
      int idx = t + q*256;
      int kk = idx >> 4, m = idx & 15;
      float sv = kscale ? kscale[k0+kk] : 1.0f;
      As[kk][m] = A[(size_t)(k0+kk)*lda + (bm+m)] * sv;
      Bs[kk][m] = B[(size_t)(k0+kk)*ldb + (bn+m)];
    }
    __syncthreads();
    #pragma unroll
    for (int kk = 0; kk < 32; kk++) acc += As[kk][tm] * Bs[kk][tn];
    __syncthreads();
  }
  atomicAdd(&Cc[(size_t)(bm+tm)*ldc + (bn+tn)], acc);
}

// paired Umu/Ulv split-K TN
__global__ __launch_bounds__(256) void k_gemm_tn_sk2(
      const float* __restrict__ A,
      const float* __restrict__ Ba, const float* __restrict__ Bb,
      float* __restrict__ Um, const float* __restrict__ kscale){
  __shared__ float As[32][17];
  __shared__ float Bs[32][17];
  int z = blockIdx.z;
  int second = z >= 16;
  int kb = (second ? z - 16 : z) * 256, ke = kb + 256;
  const float* B = second ? Bb : Ba;
  float* Cc = Um + (second ? RK*RK : 0);
  int bm = blockIdx.y*16, bn = blockIdx.x*16;
  int t = threadIdx.x;
  int tm = t >> 4, tn = t & 15;
  float acc = 0.f;
  for (int k0 = kb; k0 < ke; k0 += 32){
    #pragma unroll
    for (int q = 0; q < 2; q++){
      int idx = t + q*256;
      int kk = idx >> 4, m = idx & 15;
      As[kk][m] = A[(size_t)(k0+kk)*RK + (bm+m)] * kscale[k0+kk];
      Bs[kk][m] = B[(size_t)(k0+kk)*OUTC + (bn+m)];
    }
    __syncthreads();
    #pragma unroll
    for (int kk = 0; kk < 32; kk++) acc += As[kk][tm] * Bs[kk][tn];
    __syncthreads();
  }
  atomicAdd(&Cc[(size_t)(bm+tm)*RK + (bn+tn)], acc);
}

// ---------------- subspace chain SpMMs (4 segs/block) ----------------
__global__ __launch_bounds__(256) void k_spmm32x4(const int* __restrict__ ptr,
                       const int* __restrict__ src, const float* __restrict__ cf,
                       const float* __restrict__ X, float* __restrict__ Y){
  int seg = blockIdx.x*4 + (threadIdx.x >> 6);
  int lane = threadIdx.x & 63;
  double acc = 0.0;
  int p0 = ptr[seg], p1 = ptr[seg+1];
  for (int p = p0; p < p1; ++p){
    acc += (double)cf[p] * (double)X[(size_t)src[p]*RK + lane];
  }
  Y[(size_t)seg*RK + lane] = (float)acc;
}
__global__ __launch_bounds__(256) void k_spmm32to64x4(const int* __restrict__ ptr,
                       const int* __restrict__ src, const float* __restrict__ cf,
                       const float* __restrict__ X, double* __restrict__ Y){
  int seg = blockIdx.x*4 + (threadIdx.x >> 6);
  int lane = threadIdx.x & 63;
  double acc = 0.0;
  int p0 = ptr[seg], p1 = ptr[seg+1];
  for (int p = p0; p < p1; ++p){
    acc += (double)cf[p] * (double)X[(size_t)src[p]*RK + lane];
  }
  Y[(size_t)seg*RK + lane] = acc;
}
// Gram: G += Xslice^T Xslice
__global__ __launch_bounds__(256) void k_gram64(const double* __restrict__ X, double* __restrict__ G){
  __shared__ double Xs[64][65];
  int b = blockIdx.x;
  int t = threadIdx.x;
  #pragma unroll
  for (int q = 0; q < 16; q++){
    int idx = t + q*256;
    Xs[idx >> 6][idx & 63] = X[(size_t)(b*64 + (idx >> 6))*RK + (idx & 63)];
  }
  __syncthreads();
  int i = t >> 2;
  int j0 = (t & 3) * 16;
  double acc[16];
  #pragma unroll
  for (int jj = 0; jj < 16; jj++) acc[jj] = 0.0;
  for (int k = 0; k < 64; k++){
    double a = Xs[k][i];
    #pragma unroll
    for (int jj = 0; jj < 16; jj++) acc[jj] += a * Xs[k][j0+jj];
  }
  #pragma unroll
  for (int jj = 0; jj < 16; jj++) atomicAdd(&G[i*RK + j0 + jj], acc[jj]);
}

// ---- FUSED: block0 = Cholesky v1 (r26-proven); blocks 1..NN = h1 spmm ----
#define CHOLF_CHUNK(I0) \
  for (int k2 = 0; k2 < 16; k2++){ \
    int k = (I0) + k2; \
    int buf = k & 1; \
    if (t < 64 && j == k){ \
      double d = sqrt(fmax(cdiag, 1e-300)); \
      double s = 1.0 / d; \
      myd = d; \
      sdd[k] = s; \
      _Pragma("unroll") \
      for (int i = (I0); i < 64; i++){ c[i] *= s; colk[buf][i] = c[i]; } \
    } \
    __syncthreads(); \
    if (t < 64 && j > k && j < 64){ \
      double cj = colk[buf][j]; \
      cdiag -= cj * cj; \
      _Pragma("unroll") \
      for (int i = (I0); i < 64; i++){ c[i] -= colk[buf][i] * cj; } \
    } \
    __syncthreads(); \
  }

__global__ __launch_bounds__(256) void k_chol_spmm(
    double* __restrict__ G, double* __restrict__ sdd,
    const int* __restrict__ ptr, const int* __restrict__ src, const float* __restrict__ cf,
    const ushortT* __restrict__ Xb, float* __restrict__ Y,
    const float* __restrict__ self_dinv, const float* __restrict__ bias){
  __shared__ double colk[2][64];
  int t = threadIdx.x;
  if (blockIdx.x == 0){
    int j = t;
    double c[64];
    double cdiag = 0.0, myd = 0.0;
    if (t < 64){
      #pragma unroll
      for (int i = 0; i < 64; i++) c[i] = G[i*64 + j];
      #pragma unroll
      for (int i = 0; i < 64; i++) if (i == j) cdiag = c[i];
    }
    CHOLF_CHUNK(0)
    CHOLF_CHUNK(16)
    CHOLF_CHUNK(32)
    CHOLF_CHUNK(48)
    if (t < 64){
      #pragma unroll
      for (int i = 0; i < 64; i++){
        double v = (i > j) ? c[i] : 0.0;
        if (i == j) v = myd;
        G[i*64 + j] = v;
      }
    }
  } else {
    int seg = blockIdx.x - 1;
    float acc0, acc1;
    {
      float sd = self_dinv[seg]; float s2 = sd*sd;
      unsigned v = *(const unsigned*)&Xb[(size_t)seg*HIDC + 2*t];
      acc0 = s2 * bf2f(v & 0xffffu);
      acc1 = s2 * bf2f(v >> 16);
    }
    int p0 = ptr[seg], p1 = ptr[seg+1];
    for (int p = p0; p < p1; ++p){
      int o = src[p];
      float cc = cf[p];
      unsigned v = *(const unsigned*)&Xb[(size_t)o*HIDC + 2*t];
      acc0 += cc * bf2f(v & 0xffffu);
      acc1 += cc * bf2f(v >> 16);
    }
    acc0 += bias[2*t];
    acc1 += bias[2*t+1];
    Y[(size_t)seg*HIDC + 2*t]     = acc0;
    Y[(size_t)seg*HIDC + 2*t + 1] = acc1;
  }
}

// ---- BN partials (coalesced, r27-proven) ----
__device__ __forceinline__ void d_bnpart(int b, int t,
    const float* __restrict__ H, const int* __restrict__ y, float* __restrict__ bnsum){
  int j0 = 2*t;
  float s00=0,s01=0,s10=0,s11=0,s20=0,s21=0,s30=0,s31=0;
  float q00=0,q01=0,q10=0,q11=0,q20=0,q21=0,q30=0,q31=0;
  int r0 = b*32;
  for (int r = r0; r < r0+32; r++){
    int d = y[r];
    float2 v = *(const float2*)&H[(size_t)r*HIDC + j0];
    float ax = v.x, ay = v.y;
    float bx = ax*ax, by = ay*ay;
    if      (d == 0){ s00+=ax; s01+=ay; q00+=bx; q01+=by; }
    else if (d == 1){ s10+=ax; s11+=ay; q10+=bx; q11+=by; }
    else if (d == 2){ s20+=ax; s21+=ay; q20+=bx; q21+=by; }
    else            { s30+=ax; s31+=ay; q30+=bx; q31+=by; }
  }
  atomicAdd(&bnsum[0*HIDC+j0], s00); atomicAdd(&bnsum[0*HIDC+j0+1], s01);
  atomicAdd(&bnsum[1*HIDC+j0], s10); atomicAdd(&bnsum[1*HIDC+j0+1], s11);
  atomicAdd(&bnsum[2*HIDC+j0], s20); atomicAdd(&bnsum[2*HIDC+j0+1], s21);
  atomicAdd(&bnsum[3*HIDC+j0], s30); atomicAdd(&bnsum[3*HIDC+j0+1], s31);
  atomicAdd(&bnsum[4*HIDC+j0], q00); atomicAdd(&bnsum[4*HIDC+j0+1], q01);
  atomicAdd(&bnsum[5*HIDC+j0], q10); atomicAdd(&bnsum[5*HIDC+j0+1], q11);
  atomicAdd(&bnsum[6*HIDC+j0], q20); atomicAdd(&bnsum[6*HIDC+j0+1], q21);
  atomicAdd(&bnsum[7*HIDC+j0], q30); atomicAdd(&bnsum[7*HIDC+j0+1], q31);
}
__global__ __launch_bounds__(256) void k_bnpart(const float* __restrict__ H,
        const int* __restrict__ y, float* __restrict__ bnsum){
  d_bnpart(blockIdx.x, threadIdx.x, H, y, bnsum);
}

// ---- BN apply with inline finalize (r27-proven) ----
__device__ __forceinline__ void d_bnapply(int idx,
    float* __restrict__ H, const int* __restrict__ y,
    const float* __restrict__ bnsum, const int* __restrict__ dcnt,
    const float* __restrict__ gamma, const float* __restrict__ beta,
    ushortT* __restrict__ Hbf){
  int n = idx >> 9, j = idx & (HIDC-1);
  int d = y[n];
  float cnt  = fmaxf((float)dcnt[d], 1.0f);
  float mean = bnsum[d*HIDC + j] / cnt;
  float var  = fmaxf(bnsum[(4+d)*HIDC + j] / cnt - mean*mean, 0.f);
  float inv  = 1.0f / sqrtf(var + EPSBN);
  float gmm  = gamma[d*HIDC + j];
  float scal = gmm * inv;
  float shft = beta[d*HIDC + j] - mean * gmm * inv;
  float v = H[idx] * scal + shft;
  v = v > 0.f ? v : 0.f;
  H[idx] = v;
  Hbf[idx] = tobf(v);
}
__global__ __launch_bounds__(256) void k_bnapply(float* __restrict__ H, const int* __restrict__ y,
        const float* __restrict__ bnsum, const int* __restrict__ dcnt,
        const float* __restrict__ gamma, const float* __restrict__ beta,
        ushortT* __restrict__ Hbf){
  int idx = blockIdx.x*256 + threadIdx.x;
  if (idx < NN*HIDC) d_bnapply(idx, H, y, bnsum, dcnt, gamma, beta, Hbf);
}

// ---- FUSED: block0 = trinv (proven); blocks 1..128 = bnpart(h1) ----
__global__ __launch_bounds__(256) void k_trinv_bn(const double* __restrict__ L,
      const double* __restrict__ sdd, double* __restrict__ Rinv,
      const float* __restrict__ H, const int* __restrict__ y, float* __restrict__ bnsum){
  int t = threadIdx.x;
  if (blockIdx.x > 0){
    d_bnpart(blockIdx.x - 1, t, H, y, bnsum);
    return;
  }
  __shared__ double gl[64][65];
  __shared__ double Xl[64][65];
  __shared__ double sdinv[64];
  __shared__ double Sl[3][16][17];
  #pragma unroll
  for (int q = 0; q < 16; q++){
    int idx = t + (q << 8);
    gl[idx >> 6][idx & 63] = L[idx];
  }
  if (t < 64) sdinv[t] = sdd[t];
  for (int idx = t; idx < 64*65; idx += 256)
    ((double*)Xl)[idx] = 0.0;
  __syncthreads();
  if (t < 64){
    int b = t >> 4, c2 = t & 15;
    int g0 = b << 4;
    int gc = g0 + c2;
    Xl[gc][gc] = sdinv[gc];
    for (int i = c2 - 1; i >= 0; i--){
      int gi = g0 + i;
      double s = 0.0;
      for (int k2 = i + 1; k2 <= c2; k2++)
        s += gl[g0 + k2][gi] * Xl[g0 + k2][gc];
      Xl[gi][gc] = -s * sdinv[gi];
    }
  }
  __syncthreads();
  for (int d = 1; d < 4; d++){
    int np = 4 - d;
    int tot = np << 8;
    for (int e = t; e < tot; e += 256){
      int p = e >> 8;
      int i = (e >> 4) & 15, jj = e & 15;
      int gi = (p << 4) + i, gj = ((p + d) << 4) + jj;
      double s = 0.0;
      int a0 = (p + 1) << 4, a1 = (p + d + 1) << 4;
      for (int a = a0; a < a1; a++)
        s += gl[a][gi] * Xl[a][gj];
      Sl[p][i][jj] = s;
    }
    __syncthreads();
    for (int e = t; e < tot; e += 256){
      int p = e >> 8;
      int i = (e >> 4) & 15, jj = e & 15;
      int gi = (p << 4) + i, gj = ((p + d) << 4) + jj;
      double s = 0.0;
      #pragma unroll
      for (int k2 = 0; k2 < 16; k2++)
        s += Xl[gi][(p << 4) + k2] * Sl[p][k2][jj];
      Xl[gi][gj] = -s;
    }
    __syncthreads();
  }
  #pragma unroll
  for (int q = 0; q < 16; q++){
    int e2 = t + (q << 8);
    Rinv[e2] = Xl[e2 >> 6][e2 & 63];
  }
}

// ---- FUSED: blocks [0,1024) = applyR (+f32 Qb out); rest = bnapply(h1) ----
__global__ __launch_bounds__(256) void k_applyR_bn(const double* __restrict__ srcQ,
      const double* __restrict__ Rinv, double* __restrict__ dst, float* __restrict__ Bf1,
      float* __restrict__ H, const int* __restrict__ y,
      const float* __restrict__ bnsum, const int* __restrict__ dcnt,
      const float* __restrict__ gamma, const float* __restrict__ beta,
      ushortT* __restrict__ Hbf){
  int t = threadIdx.x;
  if (blockIdx.x >= NN/4){
    int idx = (blockIdx.x - NN/4)*256 + t;
    if (idx < NN*HIDC) d_bnapply(idx, H, y, bnsum, dcnt, gamma, beta, Hbf);
    return;
  }
  __shared__ double Rs[64][65];
  #pragma unroll
  for (int q = 0; q < 16; q++){
    int idx = t + q*256;
    Rs[idx >> 6][idx & 63] = Rinv[idx];
  }
  __syncthreads();
  int r = blockIdx.x*4 + (t >> 6);
  int j = t & 63;
  const double* rowp = srcQ + (size_t)r*RK;
  double s = 0.0;
  for (int k = 0; k <= j; k++) s += rowp[k] * Rs[k][j];
  dst[(size_t)r*RK + j] = s;
  Bf1[(size_t)r*RK + j] = (float)s;
}

// ---- FUSED: [0,64) qsum | [64,64+1024) spmmC-f32 | rest gemm_hw2(h1) ----
__global__ __launch_bounds__(256) void k_qsum_spmmC_hw2(
    const double* __restrict__ Q, double* __restrict__ qs,
    const int* __restrict__ ptr, const int* __restrict__ src, const float* __restrict__ cf,
    const float* __restrict__ Xf, float* __restrict__ Cm,
    const ushortT* __restrict__ A, const ushortT* __restrict__ Bm,
    const ushortT* __restrict__ Bl, float* __restrict__ Ca, float* __restrict__ Cb){
  int t = threadIdx.x;
  if (blockIdx.x < 64){
    int j = blockIdx.x;
    double a = 0.0;
    for (int n = t; n < NN; n += 256) a += Q[(size_t)n*RK + j];
    __shared__ double sh[256];
    sh[t] = a; __syncthreads();
    for (int off = 128; off > 0; off >>= 1){ if (t < off) sh[t] += sh[t+off]; __syncthreads(); }
    if (t == 0) qs[j] = sh[0];
    return;
  }
  if (blockIdx.x < 64 + NN/4){
    int seg = (blockIdx.x - 64)*4 + (t >> 6);
    int lane = t & 63;
    double acc = 0.0;
    int p0 = ptr[seg], p1 = ptr[seg+1];
    for (int p = p0; p < p1; ++p){
      acc += (double)cf[p] * (double)Xf[(size_t)src[p]*RK + lane];
    }
    Cm[(size_t)seg*RK + lane] = (float)acc;
    return;
  }
  d_hw2(blockIdx.x - 64 - NN/4, t, A, Bm, Bl, Ca, Cb);
}

// ---- FUSED: [0,128) fin-chores (deg2 + zero Tm/Umu/bnsum) | rest spmm2 ----
__global__ void k_fin_spmm2(
    const float* __restrict__ Cm, const double* __restrict__ qs, float* __restrict__ dinv2,
    float* __restrict__ Tm, float* __restrict__ Um, float* __restrict__ bnsum,
    const int* __restrict__ ptr, const int* __restrict__ src, const float* __restrict__ cf,
    const float* __restrict__ Xa, const float* __restrict__ Xb2,
    float* __restrict__ zout, const float* __restrict__ self_dinv,
    const float* __restrict__ bmu, const float* __restrict__ blv){
  int t = threadIdx.x;
  if (blockIdx.x < 128){
    int idx = blockIdx.x*256 + t;    // < 32768 = RK*HIDC
    Tm[idx] = 0.f;
    if (idx < 2*RK*RK) Um[idx] = 0.f;
    if (idx < 8*HIDC)  bnsum[idx] = 0.f;
    if (idx < NN){
      double s = 0.0;
      #pragma unroll
      for (int k = 0; k < RK; k++) s += (double)Cm[(size_t)idx*RK + k] * qs[k];
      dinv2[idx] = (s > 0.0) ? (float)(1.0/sqrt(s)) : 0.f;
    }
    return;
  }
  int bb = blockIdx.x - 128;         // 0 .. 2*NN/4-1
  int second = bb >= NN/4;
  int seg = (second ? bb - NN/4 : bb)*4 + (t >> 6);
  int lane = t & 63;
  const float* X = second ? Xb2 : Xa;
  const float* bias = second ? blv : bmu;
  float* Y = zout + (second ? (size_t)NN*OUTC : 0);
  float acc0;
  {
    float sd = self_dinv[seg];
    acc0 = sd*sd * X[(size_t)seg*OUTC + lane];
  }
  int p0 = ptr[seg], p1 = ptr[seg+1];
  for (int p = p0; p < p1; ++p){
    acc0 += cf[p] * X[(size_t)src[p]*OUTC + lane];
  }
  acc0 += bias[lane];
  Y[(size_t)seg*OUTC + lane] = acc0;
}

// ---------------- launch ----------------
extern "C" void kernel_launch(void* const* d_in, const int* in_sizes, int n_in,
                              void* d_out, int out_size, void* d_ws, size_t ws_size,
                              hipStream_t stream){
  (void)in_sizes; (void)n_in; (void)out_size;
  const void* x_in  = d_in[0];
  const int*  ei    = (const int*)d_in[1];
  const void* w_in  = d_in[2];
  const int*  yv    = (const int*)d_in[3];
  const void* W1i   = d_in[4];
  const void* b1i   = d_in[5];
  const void* Wmui  = d_in[6];
  const void* bmui  = d_in[7];
  const void* Wlvi  = d_in[8];
  const void* blvi  = d_in[9];
  const void* gmi   = d_in[10];
  const void* bti   = d_in[11];
  const int* rowA = ei;
  const int* colA = ei + NEDG;
  float* zout = (float*)d_out;

  // ---- workspace ----
  double* Dp = (double*)d_ws;
  size_t od = 0;
  double* Qd0 = Dp + od; od += (size_t)NN*RK;
  double* Qd1 = Dp + od; od += (size_t)NN*RK;
  double* Gd  = Dp + od; od += RK*RK;
  double* Rid = Dp + od; od += RK*RK;
  double* qsd = Dp + od; od += RK;
  double* sdd = Dp + od; od += RK;
  float* Fp = (float*)(Dp + od);
  size_t o = 0;
  float* xf   = Fp + o; o += (size_t)NN*INC;       // reused as h1/h2 buffer
  float* W1f  = Fp + o; o += (size_t)INC*HIDC;
  float* b1f  = Fp + o; o += HIDC;
  float* Wmuf = Fp + o; o += (size_t)HIDC*OUTC;
  float* bmuf = Fp + o; o += OUTC;
  float* Wlvf = Fp + o; o += (size_t)HIDC*OUTC;
  float* blvf = Fp + o; o += OUTC;
  float* gmf  = Fp + o; o += NDOM*HIDC;
  float* btf  = Fp + o; o += NDOM*HIDC;
  float* wf   = Fp + o; o += NEDG;
  float* xw1  = Fp + o; o += (size_t)NN*HIDC;
  float* hwA  = Fp + o; o += (size_t)NN*OUTC;
  float* hwB  = Fp + o; o += (size_t)NN*OUTC;
  float* Bf1  = Fp + o; o += (size_t)NN*RK;
  float* Cm   = Fp + o; o += (size_t)NN*RK;
  float* Qf0  = Fp + o; o += (size_t)NN*RK;
  float* Qf1  = Fp + o; o += (size_t)NN*RK;
  float* Tm   = Fp + o; o += (size_t)RK*HIDC;
  float* Umu  = Fp + o; o += 2*RK*RK;
  float* deg1 = Fp + o; o += NN;
  float* dinv1= Fp + o; o += NN;
  float* dinv2= Fp + o; o += NN;
  float* norm1= Fp + o; o += NEDG;
  float* bnsum= Fp + o; o += 8*HIDC;
  float* csrW = Fp + o; o += NEDG;
  float* cscW = Fp + o; o += NEDG;
  float* cscN = Fp + o; o += NEDG;
  ushortT* xbf   = (ushortT*)(Fp + o); o += (size_t)NN*INC/2;
  ushortT* W1bf  = (ushortT*)(Fp + o); o += (size_t)INC*HIDC/2;
  ushortT* xw1bf = (ushortT*)(Fp + o); o += (size_t)NN*HIDC/2;
  ushortT* hbf   = (ushortT*)(Fp + o); o += (size_t)NN*HIDC/2;
  ushortT* Wmubf = (ushortT*)(Fp + o); o += (size_t)HIDC*OUTC/2;
  ushortT* Wlvbf = (ushortT*)(Fp + o); o += (size_t)HIDC*OUTC/2;
  int* Ip = (int*)(Fp + o);
  size_t oi = 0;
  int* cntR = Ip + oi; oi += NN;
  int* ptrR = Ip + oi; oi += NN + 1;
  int* posR = Ip + oi; oi += NN;
  int* eidR = Ip + oi; oi += NEDG;
  int* cntC = Ip + oi; oi += NN;
  int* ptrC = Ip + oi; oi += NN + 1;
  int* posC = Ip + oi; oi += NN;
  int* eidC = Ip + oi; oi += NEDG;
  int* csrSrc = Ip + oi; oi += NEDG;
  int* cscSrc = Ip + oi; oi += NEDG;
  int* dcnt = Ip + oi; oi += NDOM;
  int* dflag= Ip + oi; oi += 1;

  size_t need = od*sizeof(double) + o*sizeof(float) + (oi+16)*sizeof(int);
  if (ws_size < need) return;

  float* hbuf = xf;  // x dead after xw1 GEMM

  const int T = 256;
  k_detect<<<1,T,0,stream>>>((const unsigned short*)x_in, dflag);
  k_upcast_all<<<cdiv(OFFT,T),T,0,stream>>>(
      x_in, W1i, w_in, Wmui, Wlvi, gmi, bti, b1i, bmui, blvi, dflag,
      xf, W1f, wf, Wmuf, Wlvf, gmf, btf, b1f, bmuf, blvf,
      xbf, W1bf, Wmubf, Wlvbf);

  k_prep<<<cdiv(NN,T),T,0,stream>>>(deg1, cntR, cntC, dcnt, bnsum);
  k_hist <<<cdiv(NEDG,T),T,0,stream>>>(rowA, colA, wf, deg1, cntR, cntC);
  k_dinv <<<cdiv(NN,T),T,0,stream>>>(deg1, dinv1, NN);
  k_norm1<<<cdiv(NEDG,T),T,0,stream>>>(rowA, colA, wf, dinv1, norm1);
  k_scan4096<<<1,1024,0,stream>>>(cntR, ptrR, posR);
  k_scan4096<<<1,1024,0,stream>>>(cntC, ptrC, posC);
  k_scatter<<<cdiv(NEDG,T),T,0,stream>>>(rowA, colA, posR, posC, eidR, eidC);
  k_edges<<<cdiv(NEDG,T),T,0,stream>>>(rowA, colA, wf, norm1, eidR, eidC,
                                       csrSrc, csrW, cscSrc, cscW, cscN);
  k_omega<<<cdiv(NN*RK,T),T,0,stream>>>(Qf0, Gd);  // f32 seed + Gd zero
  k_dcnt <<<cdiv(NN,T),T,0,stream>>>(yv, dcnt);

  // ---- branch-1 head ----
  k_gemm_bf16<<<dim3(HIDC/64, NN/64),256,0,stream>>>(xbf, W1bf, xw1, xw1bf);

  // ---- branch-2 subspace chain up to Gram (4 segs/block) ----
  k_spmm32x4<<<NN/4,256,0,stream>>>(ptrR, csrSrc, csrW, Qf0, Qf1);     // P1
  k_spmm32x4<<<NN/4,256,0,stream>>>(ptrC, cscSrc, cscW, Qf1, Qf0);     // P2
  k_spmm32x4<<<NN/4,256,0,stream>>>(ptrR, csrSrc, csrW, Qf0, Qf1);     // P3
  k_spmm32x4<<<NN/4,256,0,stream>>>(ptrC, cscSrc, cscW, Qf1, Qf0);     // P4
  k_spmm32to64x4<<<NN/4,256,0,stream>>>(ptrR, csrSrc, csrW, Qf0, Qd1); // P5 (f64)
  k_gram64<<<NN/64,256,0,stream>>>(Qd1, Gd);

  // ---- FUSED: chol | h1 spmm ----
  k_chol_spmm<<<NN+1,256,0,stream>>>(Gd, sdd, ptrC, cscSrc, cscN, xw1bf, hbuf,
                                     dinv1, b1f);
  // ---- FUSED: trinv | bnpart(h1) ----
  k_trinv_bn<<<1+NN/32,256,0,stream>>>(Gd, sdd, Rid, hbuf, yv, bnsum);
  // ---- FUSED: applyR (+Bf1) | bnapply(h1) ----
  k_applyR_bn<<<NN/4 + cdiv(NN*HIDC,T),256,0,stream>>>(Qd1, Rid, Qd0, Bf1,
      hbuf, yv, bnsum, dcnt, gmf, btf, hbf);
  // ---- FUSED: qsum | spmmC-f32 | gemm_hw2(h1) ----
  k_qsum_spmmC_hw2<<<64 + NN/4 + 2*(NN/64),256,0,stream>>>(Qd0, qsd,
      ptrC, cscSrc, cscW, Bf1, Cm, hbf, Wmubf, Wlvbf, hwA, hwB);
  // ---- FUSED: fin-chores | output spmm2(h1) ----
  k_fin_spmm2<<<128 + 2*(NN/4),256,0,stream>>>(Cm, qsd, dinv2, Tm, Umu, bnsum,
      ptrC, cscSrc, cscN, hwA, hwB, zout, dinv1, bmuf, blvf);

  // ---- branch-2 tail ----
  k_gemm_tn_sk<<<dim3(HIDC/16, RK/16, 8),256,0,stream>>>(RK,HIDC,NN,512, Bf1,RK, xw1,HIDC, Tm,HIDC, dinv2);
  k_gemm_nn<<<dim3(HIDC/64, NN/64),256,0,stream>>>(NN,HIDC,RK, Cm,RK, Tm,HIDC, hbuf,HIDC, dinv2, nullptr, b1f);
  k_bnpart<<<NN/32,256,0,stream>>>(hbuf, yv, bnsum);
  k_bnapply<<<cdiv(NN*HIDC,T),T,0,stream>>>(hbuf, yv, bnsum, dcnt, gmf, btf, hbf);
  k_gemm_hw2<<<2*(NN/64),256,0,stream>>>(hbf, Wmubf, Wlvbf, hwA, hwB);
  k_gemm_tn_sk2<<<dim3(RK/16, RK/16, 32),256,0,stream>>>(Bf1, hwA, hwB, Umu, dinv2);
  k_gemm_nn2<<<dim3(1, NN/64, 2),256,0,stream>>>(Cm, Umu, dinv2, bmuf, blvf, zout);
}

// Round 14
// 553.000 us; speedup vs baseline: 1.0386x; 1.0386x over previous
//
#include <hip/hip_runtime.h>
#include <hip/hip_bf16.h>

// GCNEncoder — r29: r28 regressed 556->574 (+3.2%) vs predicted gain; the
// 841us bnapply row is a replay artifact (can't fit in 574us total; code and
// env identical to r27 where it didn't chart). A/B: revert the ONE r28
// change with zero theoretical upside — P-chain 4-segs/block (block retires
// on slowest of 4 variable-degree segments, x5 serial chain) — back to
// r25-proven 64-thread/4096-block spmm. Keep f32-C gather + K4/K5 repack
// (solid theory). absmax must stay exactly 0.0078125.
// History: r28 574; r27 556; r26 578; r25 650; r22 836; r16 1138.

#define NN    4096
#define NEDG  131072
#define INC   512
#define HIDC  512
#define OUTC  64
#define RK    64
#define NDOM  4
#define EPSBN 1e-5f

typedef unsigned short ushortT;
typedef __attribute__((ext_vector_type(8))) short bf16x8;
typedef __attribute__((ext_vector_type(4))) float f32x4;

static inline int cdiv(int a, int b){ return (a + b - 1) / b; }

__device__ __forceinline__ float bf2f(unsigned u){ return __uint_as_float(u << 16); }

// ---------------- input dtype detection ----------------
__global__ __launch_bounds__(256) void k_detect(const unsigned short* __restrict__ p,
                                                int* __restrict__ flag){
  int t = threadIdx.x;
  int cnt = 0;
  for (int i = t; i < 4096; i += 256){
    unsigned short v = p[2*i];
    int e = (v >> 7) & 0xFF;
    if (e >= 100 && e <= 140) cnt++;
  }
  __shared__ int sh[256];
  sh[t] = cnt; __syncthreads();
  for (int off = 128; off > 0; off >>= 1){ if (t < off) sh[t] += sh[t+off]; __syncthreads(); }
  if (t == 0) *flag = (sh[0] >= 2048) ? 0 : 1;
}

// ---------------- fused upcast ----------------
__device__ __forceinline__ float upc1(const void* s, int f, int off){
  return f ? ((const float*)s)[off]
           : __bfloat162float(((const __hip_bfloat16*)s)[off]);
}
__device__ __forceinline__ ushortT tobf(float v){
  __hip_bfloat16 h = __float2bfloat16(v);
  return *(ushortT*)&h;
}
#define SEG_X   2097152
#define SEG_W1  262144
#define SEG_W   131072
#define SEG_WMU 32768
#define SEG_GB  2048
#define SEG_B1  512
#define SEG_BO  64
#define OFF1 (SEG_X)
#define OFF2 (OFF1+SEG_W1)
#define OFF3 (OFF2+SEG_W)
#define OFF4 (OFF3+SEG_WMU)
#define OFF5 (OFF4+SEG_WMU)
#define OFF6 (OFF5+SEG_GB)
#define OFF7 (OFF6+SEG_GB)
#define OFF8 (OFF7+SEG_B1)
#define OFF9 (OFF8+SEG_BO)
#define OFFT (OFF9+SEG_BO)

__global__ __launch_bounds__(256) void k_upcast_all(
    const void* x, const void* W1, const void* w, const void* Wmu, const void* Wlv,
    const void* gm, const void* bt, const void* b1, const void* bmu, const void* blv,
    const int* __restrict__ isf32,
    float* dx, float* dW1, float* dw, float* dWmu, float* dWlv,
    float* dgm, float* dbt, float* db1, float* dbmu, float* dblv,
    ushortT* xbf, ushortT* W1bf, ushortT* Wmubf, ushortT* Wlvbf){
  int i = blockIdx.x*256 + threadIdx.x;
  if (i >= OFFT) return;
  int f = *isf32;
  if      (i < OFF1){ float v = upc1(x, f, i); dx[i] = v; xbf[i] = tobf(v); }
  else if (i < OFF2){ float v = upc1(W1, f, i - OFF1); dW1[i - OFF1] = v; W1bf[i - OFF1] = tobf(v); }
  else if (i < OFF3) dw  [i - OFF2] = upc1(w,   f, i - OFF2);
  else if (i < OFF4){ float v = upc1(Wmu, f, i - OFF3); dWmu[i - OFF3] = v; Wmubf[i - OFF3] = tobf(v); }
  else if (i < OFF5){ float v = upc1(Wlv, f, i - OFF4); dWlv[i - OFF4] = v; Wlvbf[i - OFF4] = tobf(v); }
  else if (i < OFF6) dgm [i - OFF5] = upc1(gm,  f, i - OFF5);
  else if (i < OFF7) dbt [i - OFF6] = upc1(bt,  f, i - OFF6);
  else if (i < OFF8) db1 [i - OFF7] = upc1(b1,  f, i - OFF7);
  else if (i < OFF9) dbmu[i - OFF8] = upc1(bmu, f, i - OFF8);
  else               dblv[i - OFF9] = upc1(blv, f, i - OFF9);
}

// ---------------- small utils ----------------
__global__ __launch_bounds__(256) void k_prep(float* deg, int* cntR, int* cntC, int* dcnt,
                                              float* bnsum){
  int i = blockIdx.x*256 + threadIdx.x;
  if (i < NN){ deg[i] = 1.0f; cntR[i] = 0; cntC[i] = 0; }
  if (i < NDOM) dcnt[i] = 0;
  if (i < 8*HIDC) bnsum[i] = 0.f;
}

// ---------------- graph preprocessing ----------------
__global__ __launch_bounds__(256) void k_hist(const int* __restrict__ row, const int* __restrict__ col,
                                              const float* __restrict__ w, float* deg,
                                              int* cntR, int* cntC){
  int e = blockIdx.x*256 + threadIdx.x;
  if (e < NEDG){
    atomicAdd(&deg[col[e]], w[e]);
    atomicAdd(&cntR[row[e]], 1);
    atomicAdd(&cntC[col[e]], 1);
  }
}
__global__ __launch_bounds__(256) void k_dinv(const float* deg, float* dinv, int n){
  int i = blockIdx.x*256 + threadIdx.x;
  if (i < n){ float d = deg[i]; dinv[i] = (d > 0.f) ? 1.f/sqrtf(d) : 0.f; }
}
__global__ __launch_bounds__(256) void k_norm1(const int* __restrict__ row, const int* __restrict__ col,
                                               const float* __restrict__ w, const float* __restrict__ dinv,
                                               float* __restrict__ nrm){
  int e = blockIdx.x*256 + threadIdx.x;
  if (e < NEDG) nrm[e] = dinv[row[e]] * w[e] * dinv[col[e]];
}
__global__ __launch_bounds__(1024) void k_scan4096(const int* __restrict__ cnt,
                                                   int* __restrict__ ptr, int* __restrict__ pos){
  __shared__ int sh[1024];
  int t = threadIdx.x;
  int b = t*4;
  int a0 = cnt[b], a1 = cnt[b+1], a2 = cnt[b+2], a3 = cnt[b+3];
  sh[t] = a0 + a1 + a2 + a3;
  __syncthreads();
  for (int off = 1; off < 1024; off <<= 1){
    int v = (t >= off) ? sh[t-off] : 0;
    __syncthreads();
    sh[t] += v;
    __syncthreads();
  }
  int excl = (t == 0) ? 0 : sh[t-1];
  ptr[b]   = excl;            pos[b]   = excl;
  ptr[b+1] = excl+a0;         pos[b+1] = excl+a0;
  ptr[b+2] = excl+a0+a1;      pos[b+2] = excl+a0+a1;
  ptr[b+3] = excl+a0+a1+a2;   pos[b+3] = excl+a0+a1+a2;
  if (t == 1023) ptr[4096] = sh[1023];
}
__global__ __launch_bounds__(256) void k_scatter(const int* __restrict__ row, const int* __restrict__ col,
                                                 int* posR, int* posC, int* eidR, int* eidC){
  int e = blockIdx.x*256 + threadIdx.x;
  if (e < NEDG){
    int p = atomicAdd(&posR[row[e]], 1); eidR[p] = e;
    int q = atomicAdd(&posC[col[e]], 1); eidC[q] = e;
  }
}
__global__ __launch_bounds__(256) void k_edges(const int* __restrict__ rowA, const int* __restrict__ colA,
        const float* __restrict__ wf, const float* __restrict__ nrm,
        const int* __restrict__ eidR, const int* __restrict__ eidC,
        int* __restrict__ csrSrc, float* __restrict__ csrW,
        int* __restrict__ cscSrc, float* __restrict__ cscW, float* __restrict__ cscN){
  int p = blockIdx.x*256 + threadIdx.x;
  if (p < NEDG){
    int eR = eidR[p]; csrSrc[p] = colA[eR]; csrW[p] = wf[eR];
    int eC = eidC[p]; cscSrc[p] = rowA[eC]; cscW[p] = wf[eC]; cscN[p] = nrm[eC];
  }
}
__global__ __launch_bounds__(256) void k_dcnt(const int* __restrict__ y, int* dcnt){
  int i = blockIdx.x*256 + threadIdx.x;
  if (i < NN) atomicAdd(&dcnt[y[i]], 1);
}

// ---------------- threefry2x32 (KAT-verified) ----------------
__device__ __forceinline__ unsigned rotl32(unsigned x, unsigned d){ return (x << d) | (x >> (32u - d)); }
#define TF_ROUND4(R0,R1,R2,R3) \
  x0 += x1; x1 = rotl32(x1,R0); x1 ^= x0; \
  x0 += x1; x1 = rotl32(x1,R1); x1 ^= x0; \
  x0 += x1; x1 = rotl32(x1,R2); x1 ^= x0; \
  x0 += x1; x1 = rotl32(x1,R3); x1 ^= x0;

__device__ __forceinline__ void tf2x32(unsigned k0, unsigned k1, unsigned c0, unsigned c1,
                                       unsigned* o0, unsigned* o1){
  unsigned ks2 = 0x1BD11BDAu ^ k0 ^ k1;
  unsigned x0 = c0 + k0, x1 = c1 + k1;
  TF_ROUND4(13,15,26,6);   x0 += k1;  x1 += ks2 + 1u;
  TF_ROUND4(17,29,16,24);  x0 += ks2; x1 += k0 + 2u;
  TF_ROUND4(13,15,26,6);   x0 += k0;  x1 += k1 + 3u;
  TF_ROUND4(17,29,16,24);  x0 += k1;  x1 += ks2 + 4u;
  TF_ROUND4(13,15,26,6);   x0 += ks2; x1 += k0 + 5u;
  *o0 = x0; *o1 = x1;
}

// ---------------- omega (verified; f32 out; + Gd zero fold) ----------------
__device__ double erfinv64(double x){
  double w = -log1p(-x*x);
  double p;
  if (w < 5.0){
    w -= 2.5;
    p = 2.81022636e-08;  p = p*w + 3.43273939e-07; p = p*w - 3.5233877e-06;
    p = p*w - 4.39150654e-06; p = p*w + 0.00021858087; p = p*w - 0.00125372503;
    p = p*w - 0.00417768164;  p = p*w + 0.246640727;   p = p*w + 1.50140941;
  } else {
    w = sqrt(w) - 3.0;
    p = -0.000200214257; p = p*w + 0.000100950558; p = p*w + 0.00134934322;
    p = p*w - 0.00367342844; p = p*w + 0.00573950773; p = p*w - 0.0076224613;
    p = p*w + 0.00943887047; p = p*w + 1.00167406;    p = p*w + 2.83297682;
  }
  double y = p * x;
  const double c = 1.1283791670955126;   // 2/sqrt(pi)
  #pragma unroll
  for (int it = 0; it < 3; it++){
    double err = erf(y) - x;
    y -= err / (c * exp(-y*y));
  }
  return y;
}

__device__ float bits_to_normal(unsigned b){
  float f = __uint_as_float((b >> 9) | 0x3f800000u) - 1.0f;
  const float lo = -0.99999994f;
  float x = fmaxf(lo, f * 2.0f + lo);
  double r = 1.4142135623730951 * erfinv64((double)x);
  return (float)r;
}

__global__ __launch_bounds__(256) void k_omega(float* __restrict__ om, double* __restrict__ Gd){
  int i = blockIdx.x*256 + threadIdx.x;
  if (i < RK*RK) Gd[i] = 0.0;
  if (i >= 262144) return;
  unsigned o0, o1;
  tf2x32(0u, 42u, 0u, (unsigned)i, &o0, &o1);
  om[i] = bits_to_normal(o0 ^ o1);
}

// ---------------- bf16 MFMA GEMM (r22-proven) + bf16 C copy ----------------
__global__ __launch_bounds__(256) void k_gemm_bf16(
    const ushortT* __restrict__ A, const ushortT* __restrict__ B,
    float* __restrict__ Cc, ushortT* __restrict__ Cbf){
  __shared__ ushortT As2[64][40];
  __shared__ ushortT Bs2[64][40];
  int t = threadIdx.x;
  int bm = blockIdx.y * 64, bn = blockIdx.x * 64;
  int w = t >> 6, l = t & 63;
  int lr = l & 15, lk = l >> 4;
  f32x4 acc[4] = {};
  int ar = t >> 2, ac = (t & 3) * 8;
  int bc = t & 63, bk = (t >> 6) * 8;
  for (int k0 = 0; k0 < 512; k0 += 32){
    *(uint4*)&As2[ar][ac] = *(const uint4*)&A[(size_t)(bm + ar) * 512 + k0 + ac];
    ushortT tmp[8];
    #pragma unroll
    for (int j = 0; j < 8; j++)
      tmp[j] = B[(size_t)(k0 + bk + j) * 512 + bn + bc];
    *(uint4*)&Bs2[bc][bk] = *(uint4*)tmp;
    __syncthreads();
    bf16x8 afrag = *(bf16x8*)&As2[w * 16 + lr][lk * 8];
    #pragma unroll
    for (int nt = 0; nt < 4; nt++){
      bf16x8 bfrag = *(bf16x8*)&Bs2[nt * 16 + lr][lk * 8];
      acc[nt] = __builtin_amdgcn_mfma_f32_16x16x32_bf16(afrag, bfrag, acc[nt], 0, 0, 0);
    }
    __syncthreads();
  }
  #pragma unroll
  for (int nt = 0; nt < 4; nt++){
    #pragma unroll
    for (int i = 0; i < 4; i++){
      size_t idx = (size_t)(bm + w * 16 + lk * 4 + i) * 512 + bn + nt * 16 + lr;
      float v = acc[nt][i];
      Cc[idx] = v;
      Cbf[idx] = tobf(v);
    }
  }
}

// device body: paired hw GEMM
__device__ __forceinline__ void d_hw2(int bx, int t,
    const ushortT* __restrict__ A, const ushortT* __restrict__ Bm,
    const ushortT* __restrict__ Bl, float* __restrict__ Ca, float* __restrict__ Cb){
  __shared__ ushortT As2[64][40];
  __shared__ ushortT Bs2[64][40];
  int nb = NN/64;
  int second = bx >= nb;
  int bm = (bx - (second ? nb : 0)) * 64;
  const ushortT* B = second ? Bl : Bm;
  float* Cc = second ? Cb : Ca;
  int w = t >> 6, l = t & 63;
  int lr = l & 15, lk = l >> 4;
  f32x4 acc[4] = {};
  int ar = t >> 2, ac = (t & 3) * 8;
  int bc = t & 63, bk = (t >> 6) * 8;
  for (int k0 = 0; k0 < 512; k0 += 32){
    *(uint4*)&As2[ar][ac] = *(const uint4*)&A[(size_t)(bm + ar) * 512 + k0 + ac];
    ushortT tmp[8];
    #pragma unroll
    for (int j = 0; j < 8; j++)
      tmp[j] = B[(size_t)(k0 + bk + j) * 64 + bc];
    *(uint4*)&Bs2[bc][bk] = *(uint4*)tmp;
    __syncthreads();
    bf16x8 afrag = *(bf16x8*)&As2[w * 16 + lr][lk * 8];
    #pragma unroll
    for (int nt = 0; nt < 4; nt++){
      bf16x8 bfrag = *(bf16x8*)&Bs2[nt * 16 + lr][lk * 8];
      acc[nt] = __builtin_amdgcn_mfma_f32_16x16x32_bf16(afrag, bfrag, acc[nt], 0, 0, 0);
    }
    __syncthreads();
  }
  #pragma unroll
  for (int nt = 0; nt < 4; nt++){
    #pragma unroll
    for (int i = 0; i < 4; i++){
      Cc[(size_t)(bm + w * 16 + lk * 4 + i) * 64 + nt * 16 + lr] = acc[nt][i];
    }
  }
}
__global__ __launch_bounds__(256) void k_gemm_hw2(
    const ushortT* __restrict__ A, const ushortT* __restrict__ Bm,
    const ushortT* __restrict__ Bl, float* __restrict__ Ca, float* __restrict__ Cb){
  d_hw2(blockIdx.x, threadIdx.x, A, Bm, Bl, Ca, Cb);
}

// ---------------- GEMM (fp32, h2 dense) ----------------
__global__ __launch_bounds__(256) void k_gemm_nn(int M, int Nn, int K,
      const float* __restrict__ A, int lda, const float* __restrict__ B, int ldb,
      float* __restrict__ Cc, int ldc, const float* __restrict__ rowscale,
      const float* __restrict__ kscale, const float* __restrict__ bias){
  __shared__ float As[16][65];
  __shared__ float Bs[16][65];
  int bm = blockIdx.y*64, bn = blockIdx.x*64;
  int t = threadIdx.x;
  int tr = t >> 4, tc = t & 15;
  float acc[4][4] = {};
  for (int k0 = 0; k0 < K; k0 += 16){
    #pragma unroll
    for (int q = 0; q < 4; q++){
      int idx = t*4 + q;
      int m = idx >> 4, kk = idx & 15;
      As[kk][m] = A[(size_t)(bm+m)*lda + (k0+kk)];
    }
    #pragma unroll
    for (int q = 0; q < 4; q++){
      int idx = t + q*256;
      int kk = idx >> 6, n = idx & 63;
      float ks = kscale ? kscale[k0+kk] : 1.0f;
      Bs[kk][n] = B[(size_t)(k0+kk)*ldb + (bn+n)] * ks;
    }
    __syncthreads();
    #pragma unroll
    for (int kk = 0; kk < 16; kk++){
      float a0 = As[kk][tr*4+0], a1 = As[kk][tr*4+1], a2 = As[kk][tr*4+2], a3 = As[kk][tr*4+3];
      float b0 = Bs[kk][tc*4+0], b1 = Bs[kk][tc*4+1], b2 = Bs[kk][tc*4+2], b3 = Bs[kk][tc*4+3];
      acc[0][0] += a0*b0; acc[0][1] += a0*b1; acc[0][2] += a0*b2; acc[0][3] += a0*b3;
      acc[1][0] += a1*b0; acc[1][1] += a1*b1; acc[1][2] += a1*b2; acc[1][3] += a1*b3;
      acc[2][0] += a2*b0; acc[2][1] += a2*b1; acc[2][2] += a2*b2; acc[2][3] += a2*b3;
      acc[3][0] += a3*b0; acc[3][1] += a3*b1; acc[3][2] += a3*b2; acc[3][3] += a3*b3;
    }
    __syncthreads();
  }
  #pragma unroll
  for (int i2 = 0; i2 < 4; i2++){
    int m = bm + tr*4 + i2;
    float rs = rowscale ? rowscale[m] : 1.0f;
    #pragma unroll
    for (int j2 = 0; j2 < 4; j2++){
      int n = bn + tc*4 + j2;
      float v = acc[i2][j2] * rs;
      if (bias) v += bias[n];
      Cc[(size_t)m*ldc + n] = v;
    }
  }
}

// paired zout2/zout3 GEMMs
__global__ __launch_bounds__(256) void k_gemm_nn2(
      const float* __restrict__ A, const float* __restrict__ Um,
      const float* __restrict__ rowscale,
      const float* __restrict__ bmu, const float* __restrict__ blv,
      float* __restrict__ zout){
  __shared__ float As[16][65];
  __shared__ float Bs[16][65];
  int z = blockIdx.z;
  const float* B = Um + (size_t)z*RK*RK;
  const float* bias = z ? blv : bmu;
  float* Cc = zout + (size_t)(2+z)*NN*OUTC;
  int bm = blockIdx.y*64;
  int t = threadIdx.x;
  int tr = t >> 4, tc = t & 15;
  float acc[4][4] = {};
  for (int k0 = 0; k0 < RK; k0 += 16){
    #pragma unroll
    for (int q = 0; q < 4; q++){
      int idx = t*4 + q;
      int m = idx >> 4, kk = idx & 15;
      As[kk][m] = A[(size_t)(bm+m)*RK + (k0+kk)];
    }
    #pragma unroll
    for (int q = 0; q < 4; q++){
      int idx = t + q*256;
      int kk = idx >> 6, n = idx & 63;
      Bs[kk][n] = B[(size_t)(k0+kk)*RK + n];
    }
    __syncthreads();
    #pragma unroll
    for (int kk = 0; kk < 16; kk++){
      float a0 = As[kk][tr*4+0], a1 = As[kk][tr*4+1], a2 = As[kk][tr*4+2], a3 = As[kk][tr*4+3];
      float b0 = Bs[kk][tc*4+0], b1 = Bs[kk][tc*4+1], b2 = Bs[kk][tc*4+2], b3 = Bs[kk][tc*4+3];
      acc[0][0] += a0*b0; acc[0][1] += a0*b1; acc[0][2] += a0*b2; acc[0][3] += a0*b3;
      acc[1][0] += a1*b0; acc[1][1] += a1*b1; acc[1][2] += a1*b2; acc[1][3] += a1*b3;
      acc[2][0] += a2*b0; acc[2][1] += a2*b1; acc[2][2] += a2*b2; acc[2][3] += a2*b3;
      acc[3][0] += a3*b0; acc[3][1] += a3*b1; acc[3][2] += a3*b2; acc[3][3] += a3*b3;
    }
    __syncthreads();
  }
  #pragma unroll
  for (int i2 = 0; i2 < 4; i2++){
    int m = bm + tr*4 + i2;
    float rs = rowscale[m];
    #pragma unroll
    for (int j2 = 0; j2 < 4; j2++){
      int n = tc*4 + j2;
      Cc[(size_t)m*OUTC + n] = acc[i2][j2] * rs + bias[n];
    }
  }
}

// split-K TN (Tm)
__global__ __launch_bounds__(256) void k_gemm_tn_sk(int M, int Nn, int K, int kchunk,
      const float* __restrict__ A, int lda, const float* __restrict__ B, int ldb,
      float* __restrict__ Cc, int ldc, const float* __restrict__ kscale){
  __shared__ float As[32][17];
  __shared__ float Bs[32][17];
  int bm = blockIdx.y*16, bn = blockIdx.x*16;
  int kb = blockIdx.z*kchunk, ke = kb + kchunk;
  int t = threadIdx.x;
  int tm = t >> 4, tn = t & 15;
  float acc = 0.f;
  for (int k0 = kb; k0 < ke; k0 += 32){
    #pragma unroll
    for (int q = 0; q < 2; q++){
      int idx = t + q*256;
      int kk = idx >> 4, m = idx & 15;
      float sv = kscale ? kscale[k0+kk] : 1.0f;
      As[kk][m] = A[(size_t)(k0+kk)*lda + (bm+m)] * sv;
      Bs[kk][m] = B[(size_t)(k0+kk)*ldb + (bn+m)];
    }
    __syncthreads();
    #pragma unroll
    for (int kk = 0; kk < 32; kk++) acc += As[kk][tm] * Bs[kk][tn];
    __syncthreads();
  }
  atomicAdd(&Cc[(size_t)(bm+tm)*ldc + (bn+tn)], acc);
}

// paired Umu/Ulv split-K TN
__global__ __launch_bounds__(256) void k_gemm_tn_sk2(
      const float* __restrict__ A,
      const float* __restrict__ Ba, const float* __restrict__ Bb,
      float* __restrict__ Um, const float* __restrict__ kscale){
  __shared__ float As[32][17];
  __shared__ float Bs[32][17];
  int z = blockIdx.z;
  int second = z >= 16;
  int kb = (second ? z - 16 : z) * 256, ke = kb + 256;
  const float* B = second ? Bb : Ba;
  float* Cc = Um + (second ? RK*RK : 0);
  int bm = blockIdx.y*16, bn = blockIdx.x*16;
  int t = threadIdx.x;
  int tm = t >> 4, tn = t & 15;
  float acc = 0.f;
  for (int k0 = kb; k0 < ke; k0 += 32){
    #pragma unroll
    for (int q = 0; q < 2; q++){
      int idx = t + q*256;
      int kk = idx >> 4, m = idx & 15;
      As[kk][m] = A[(size_t)(k0+kk)*RK + (bm+m)] * kscale[k0+kk];
      Bs[kk][m] = B[(size_t)(k0+kk)*OUTC + (bn+m)];
    }
    __syncthreads();
    #pragma unroll
    for (int kk = 0; kk < 32; kk++) acc += As[kk][tm] * Bs[kk][tn];
    __syncthreads();
  }
  atomicAdd(&Cc[(size_t)(bm+tm)*RK + (bn+tn)], acc);
}

// ---------------- subspace chain SpMMs (r25-proven 64-thread blocks) ----------------
__global__ __launch_bounds__(64) void k_spmm32(const int* __restrict__ ptr,
                       const int* __restrict__ src, const float* __restrict__ cf,
                       const float* __restrict__ X, float* __restrict__ Y){
  int seg = blockIdx.x;
  int t = threadIdx.x;
  double acc = 0.0;
  int p0 = ptr[seg], p1 = ptr[seg+1];
  for (int p = p0; p < p1; ++p){
    acc += (double)cf[p] * (double)X[(size_t)src[p]*RK + t];
  }
  Y[(size_t)seg*RK + t] = (float)acc;
}
__global__ __launch_bounds__(64) void k_spmm32to64(const int* __restrict__ ptr,
                       const int* __restrict__ src, const float* __restrict__ cf,
                       const float* __restrict__ X, double* __restrict__ Y){
  int seg = blockIdx.x;
  int t = threadIdx.x;
  double acc = 0.0;
  int p0 = ptr[seg], p1 = ptr[seg+1];
  for (int p = p0; p < p1; ++p){
    acc += (double)cf[p] * (double)X[(size_t)src[p]*RK + t];
  }
  Y[(size_t)seg*RK + t] = acc;
}
// Gram: G += Xslice^T Xslice
__global__ __launch_bounds__(256) void k_gram64(const double* __restrict__ X, double* __restrict__ G){
  __shared__ double Xs[64][65];
  int b = blockIdx.x;
  int t = threadIdx.x;
  #pragma unroll
  for (int q = 0; q < 16; q++){
    int idx = t + q*256;
    Xs[idx >> 6][idx & 63] = X[(size_t)(b*64 + (idx >> 6))*RK + (idx & 63)];
  }
  __syncthreads();
  int i = t >> 2;
  int j0 = (t & 3) * 16;
  double acc[16];
  #pragma unroll
  for (int jj = 0; jj < 16; jj++) acc[jj] = 0.0;
  for (int k = 0; k < 64; k++){
    double a = Xs[k][i];
    #pragma unroll
    for (int jj = 0; jj < 16; jj++) acc[jj] += a * Xs[k][j0+jj];
  }
  #pragma unroll
  for (int jj = 0; jj < 16; jj++) atomicAdd(&G[i*RK + j0 + jj], acc[jj]);
}

// ---- FUSED: block0 = Cholesky v1 (r26-proven); blocks 1..NN = h1 spmm ----
#define CHOLF_CHUNK(I0) \
  for (int k2 = 0; k2 < 16; k2++){ \
    int k = (I0) + k2; \
    int buf = k & 1; \
    if (t < 64 && j == k){ \
      double d = sqrt(fmax(cdiag, 1e-300)); \
      double s = 1.0 / d; \
      myd = d; \
      sdd[k] = s; \
      _Pragma("unroll") \
      for (int i = (I0); i < 64; i++){ c[i] *= s; colk[buf][i] = c[i]; } \
    } \
    __syncthreads(); \
    if (t < 64 && j > k && j < 64){ \
      double cj = colk[buf][j]; \
      cdiag -= cj * cj; \
      _Pragma("unroll") \
      for (int i = (I0); i < 64; i++){ c[i] -= colk[buf][i] * cj; } \
    } \
    __syncthreads(); \
  }

__global__ __launch_bounds__(256) void k_chol_spmm(
    double* __restrict__ G, double* __restrict__ sdd,
    const int* __restrict__ ptr, const int* __restrict__ src, const float* __restrict__ cf,
    const ushortT* __restrict__ Xb, float* __restrict__ Y,
    const float* __restrict__ self_dinv, const float* __restrict__ bias){
  __shared__ double colk[2][64];
  int t = threadIdx.x;
  if (blockIdx.x == 0){
    int j = t;
    double c[64];
    double cdiag = 0.0, myd = 0.0;
    if (t < 64){
      #pragma unroll
      for (int i = 0; i < 64; i++) c[i] = G[i*64 + j];
      #pragma unroll
      for (int i = 0; i < 64; i++) if (i == j) cdiag = c[i];
    }
    CHOLF_CHUNK(0)
    CHOLF_CHUNK(16)
    CHOLF_CHUNK(32)
    CHOLF_CHUNK(48)
    if (t < 64){
      #pragma unroll
      for (int i = 0; i < 64; i++){
        double v = (i > j) ? c[i] : 0.0;
        if (i == j) v = myd;
        G[i*64 + j] = v;
      }
    }
  } else {
    int seg = blockIdx.x - 1;
    float acc0, acc1;
    {
      float sd = self_dinv[seg]; float s2 = sd*sd;
      unsigned v = *(const unsigned*)&Xb[(size_t)seg*HIDC + 2*t];
      acc0 = s2 * bf2f(v & 0xffffu);
      acc1 = s2 * bf2f(v >> 16);
    }
    int p0 = ptr[seg], p1 = ptr[seg+1];
    for (int p = p0; p < p1; ++p){
      int o = src[p];
      float cc = cf[p];
      unsigned v = *(const unsigned*)&Xb[(size_t)o*HIDC + 2*t];
      acc0 += cc * bf2f(v & 0xffffu);
      acc1 += cc * bf2f(v >> 16);
    }
    acc0 += bias[2*t];
    acc1 += bias[2*t+1];
    Y[(size_t)seg*HIDC + 2*t]     = acc0;
    Y[(size_t)seg*HIDC + 2*t + 1] = acc1;
  }
}

// ---- BN partials (coalesced, r27-proven) ----
__device__ __forceinline__ void d_bnpart(int b, int t,
    const float* __restrict__ H, const int* __restrict__ y, float* __restrict__ bnsum){
  int j0 = 2*t;
  float s00=0,s01=0,s10=0,s11=0,s20=0,s21=0,s30=0,s31=0;
  float q00=0,q01=0,q10=0,q11=0,q20=0,q21=0,q30=0,q31=0;
  int r0 = b*32;
  for (int r = r0; r < r0+32; r++){
    int d = y[r];
    float2 v = *(const float2*)&H[(size_t)r*HIDC + j0];
    float ax = v.x, ay = v.y;
    float bx = ax*ax, by = ay*ay;
    if      (d == 0){ s00+=ax; s01+=ay; q00+=bx; q01+=by; }
    else if (d == 1){ s10+=ax; s11+=ay; q10+=bx; q11+=by; }
    else if (d == 2){ s20+=ax; s21+=ay; q20+=bx; q21+=by; }
    else            { s30+=ax; s31+=ay; q30+=bx; q31+=by; }
  }
  atomicAdd(&bnsum[0*HIDC+j0], s00); atomicAdd(&bnsum[0*HIDC+j0+1], s01);
  atomicAdd(&bnsum[1*HIDC+j0], s10); atomicAdd(&bnsum[1*HIDC+j0+1], s11);
  atomicAdd(&bnsum[2*HIDC+j0], s20); atomicAdd(&bnsum[2*HIDC+j0+1], s21);
  atomicAdd(&bnsum[3*HIDC+j0], s30); atomicAdd(&bnsum[3*HIDC+j0+1], s31);
  atomicAdd(&bnsum[4*HIDC+j0], q00); atomicAdd(&bnsum[4*HIDC+j0+1], q01);
  atomicAdd(&bnsum[5*HIDC+j0], q10); atomicAdd(&bnsum[5*HIDC+j0+1], q11);
  atomicAdd(&bnsum[6*HIDC+j0], q20); atomicAdd(&bnsum[6*HIDC+j0+1], q21);
  atomicAdd(&bnsum[7*HIDC+j0], q30); atomicAdd(&bnsum[7*HIDC+j0+1], q31);
}
__global__ __launch_bounds__(256) void k_bnpart(const float* __restrict__ H,
        const int* __restrict__ y, float* __restrict__ bnsum){
  d_bnpart(blockIdx.x, threadIdx.x, H, y, bnsum);
}

// ---- BN apply with inline finalize (r27-proven) ----
__device__ __forceinline__ void d_bnapply(int idx,
    float* __restrict__ H, const int* __restrict__ y,
    const float* __restrict__ bnsum, const int* __restrict__ dcnt,
    const float* __restrict__ gamma, const float* __restrict__ beta,
    ushortT* __restrict__ Hbf){
  int n = idx >> 9, j = idx & (HIDC-1);
  int d = y[n];
  float cnt  = fmaxf((float)dcnt[d], 1.0f);
  float mean = bnsum[d*HIDC + j] / cnt;
  float var  = fmaxf(bnsum[(4+d)*HIDC + j] / cnt - mean*mean, 0.f);
  float inv  = 1.0f / sqrtf(var + EPSBN);
  float gmm  = gamma[d*HIDC + j];
  float scal = gmm * inv;
  float shft = beta[d*HIDC + j] - mean * gmm * inv;
  float v = H[idx] * scal + shft;
  v = v > 0.f ? v : 0.f;
  H[idx] = v;
  Hbf[idx] = tobf(v);
}
__global__ __launch_bounds__(256) void k_bnapply(float* __restrict__ H, const int* __restrict__ y,
        const float* __restrict__ bnsum, const int* __restrict__ dcnt,
        const float* __restrict__ gamma, const float* __restrict__ beta,
        ushortT* __restrict__ Hbf){
  int idx = blockIdx.x*256 + threadIdx.x;
  if (idx < NN*HIDC) d_bnapply(idx, H, y, bnsum, dcnt, gamma, beta, Hbf);
}

// ---- FUSED: block0 = trinv (proven); blocks 1..128 = bnpart(h1) ----
__global__ __launch_bounds__(256) void k_trinv_bn(const double* __restrict__ L,
      const double* __restrict__ sdd, double* __restrict__ Rinv,
      const float* __restrict__ H, const int* __restrict__ y, float* __restrict__ bnsum){
  int t = threadIdx.x;
  if (blockIdx.x > 0){
    d_bnpart(blockIdx.x - 1, t, H, y, bnsum);
    return;
  }
  __shared__ double gl[64][65];
  __shared__ double Xl[64][65];
  __shared__ double sdinv[64];
  __shared__ double Sl[3][16][17];
  #pragma unroll
  for (int q = 0; q < 16; q++){
    int idx = t + (q << 8);
    gl[idx >> 6][idx & 63] = L[idx];
  }
  if (t < 64) sdinv[t] = sdd[t];
  for (int idx = t; idx < 64*65; idx += 256)
    ((double*)Xl)[idx] = 0.0;
  __syncthreads();
  if (t < 64){
    int b = t >> 4, c2 = t & 15;
    int g0 = b << 4;
    int gc = g0 + c2;
    Xl[gc][gc] = sdinv[gc];
    for (int i = c2 - 1; i >= 0; i--){
      int gi = g0 + i;
      double s = 0.0;
      for (int k2 = i + 1; k2 <= c2; k2++)
        s += gl[g0 + k2][gi] * Xl[g0 + k2][gc];
      Xl[gi][gc] = -s * sdinv[gi];
    }
  }
  __syncthreads();
  for (int d = 1; d < 4; d++){
    int np = 4 - d;
    int tot = np << 8;
    for (int e = t; e < tot; e += 256){
      int p = e >> 8;
      int i = (e >> 4) & 15, jj = e & 15;
      int gi = (p << 4) + i, gj = ((p + d) << 4) + jj;
      double s = 0.0;
      int a0 = (p + 1) << 4, a1 = (p + d + 1) << 4;
      for (int a = a0; a < a1; a++)
        s += gl[a][gi] * Xl[a][gj];
      Sl[p][i][jj] = s;
    }
    __syncthreads();
    for (int e = t; e < tot; e += 256){
      int p = e >> 8;
      int i = (e >> 4) & 15, jj = e & 15;
      int gi = (p << 4) + i, gj = ((p + d) << 4) + jj;
      double s = 0.0;
      #pragma unroll
      for (int k2 = 0; k2 < 16; k2++)
        s += Xl[gi][(p << 4) + k2] * Sl[p][k2][jj];
      Xl[gi][gj] = -s;
    }
    __syncthreads();
  }
  #pragma unroll
  for (int q = 0; q < 16; q++){
    int e2 = t + (q << 8);
    Rinv[e2] = Xl[e2 >> 6][e2 & 63];
  }
}

// ---- FUSED: blocks [0,1024) = applyR (+f32 Qb out); rest = bnapply(h1) ----
__global__ __launch_bounds__(256) void k_applyR_bn(const double* __restrict__ srcQ,
      const double* __restrict__ Rinv, double* __restrict__ dst, float* __restrict__ Bf1,
      float* __restrict__ H, const int* __restrict__ y,
      const float* __restrict__ bnsum, const int* __restrict__ dcnt,
      const float* __restrict__ gamma, const float* __restrict__ beta,
      ushortT* __restrict__ Hbf){
  int t = threadIdx.x;
  if (blockIdx.x >= NN/4){
    int idx = (blockIdx.x - NN/4)*256 + t;
    if (idx < NN*HIDC) d_bnapply(idx, H, y, bnsum, dcnt, gamma, beta, Hbf);
    return;
  }
  __shared__ double Rs[64][65];
  #pragma unroll
  for (int q = 0; q < 16; q++){
    int idx = t + q*256;
    Rs[idx >> 6][idx & 63] = Rinv[idx];
  }
  __syncthreads();
  int r = blockIdx.x*4 + (t >> 6);
  int j = t & 63;
  const double* rowp = srcQ + (size_t)r*RK;
  double s = 0.0;
  for (int k = 0; k <= j; k++) s += rowp[k] * Rs[k][j];
  dst[(size_t)r*RK + j] = s;
  Bf1[(size_t)r*RK + j] = (float)s;
}

// ---- FUSED: [0,64) qsum | [64,64+1024) spmmC-f32 | rest gemm_hw2(h1) ----
__global__ __launch_bounds__(256) void k_qsum_spmmC_hw2(
    const double* __restrict__ Q, double* __restrict__ qs,
    const int* __restrict__ ptr, const int* __restrict__ src, const float* __restrict__ cf,
    const float* __restrict__ Xf, float* __restrict__ Cm,
    const ushortT* __restrict__ A, const ushortT* __restrict__ Bm,
    const ushortT* __restrict__ Bl, float* __restrict__ Ca, float* __restrict__ Cb){
  int t = threadIdx.x;
  if (blockIdx.x < 64){
    int j = blockIdx.x;
    double a = 0.0;
    for (int n = t; n < NN; n += 256) a += Q[(size_t)n*RK + j];
    __shared__ double sh[256];
    sh[t] = a; __syncthreads();
    for (int off = 128; off > 0; off >>= 1){ if (t < off) sh[t] += sh[t+off]; __syncthreads(); }
    if (t == 0) qs[j] = sh[0];
    return;
  }
  if (blockIdx.x < 64 + NN/4){
    int seg = (blockIdx.x - 64)*4 + (t >> 6);
    int lane = t & 63;
    double acc = 0.0;
    int p0 = ptr[seg], p1 = ptr[seg+1];
    for (int p = p0; p < p1; ++p){
      acc += (double)cf[p] * (double)Xf[(size_t)src[p]*RK + lane];
    }
    Cm[(size_t)seg*RK + lane] = (float)acc;
    return;
  }
  d_hw2(blockIdx.x - 64 - NN/4, t, A, Bm, Bl, Ca, Cb);
}

// ---- FUSED: [0,128) fin-chores (deg2 + zero Tm/Umu/bnsum) | rest spmm2 ----
__global__ void k_fin_spmm2(
    const float* __restrict__ Cm, const double* __restrict__ qs, float* __restrict__ dinv2,
    float* __restrict__ Tm, float* __restrict__ Um, float* __restrict__ bnsum,
    const int* __restrict__ ptr, const int* __restrict__ src, const float* __restrict__ cf,
    const float* __restrict__ Xa, const float* __restrict__ Xb2,
    float* __restrict__ zout, const float* __restrict__ self_dinv,
    const float* __restrict__ bmu, const float* __restrict__ blv){
  int t = threadIdx.x;
  if (blockIdx.x < 128){
    int idx = blockIdx.x*256 + t;    // < 32768 = RK*HIDC
    Tm[idx] = 0.f;
    if (idx < 2*RK*RK) Um[idx] = 0.f;
    if (idx < 8*HIDC)  bnsum[idx] = 0.f;
    if (idx < NN){
      double s = 0.0;
      #pragma unroll
      for (int k = 0; k < RK; k++) s += (double)Cm[(size_t)idx*RK + k] * qs[k];
      dinv2[idx] = (s > 0.0) ? (float)(1.0/sqrt(s)) : 0.f;
    }
    return;
  }
  int bb = blockIdx.x - 128;         // 0 .. 2*NN/4-1
  int second = bb >= NN/4;
  int seg = (second ? bb - NN/4 : bb)*4 + (t >> 6);
  int lane = t & 63;
  const float* X = second ? Xb2 : Xa;
  const float* bias = second ? blv : bmu;
  float* Y = zout + (second ? (size_t)NN*OUTC : 0);
  float acc0;
  {
    float sd = self_dinv[seg];
    acc0 = sd*sd * X[(size_t)seg*OUTC + lane];
  }
  int p0 = ptr[seg], p1 = ptr[seg+1];
  for (int p = p0; p < p1; ++p){
    acc0 += cf[p] * X[(size_t)src[p]*OUTC + lane];
  }
  acc0 += bias[lane];
  Y[(size_t)seg*OUTC + lane] = acc0;
}

// ---------------- launch ----------------
extern "C" void kernel_launch(void* const* d_in, const int* in_sizes, int n_in,
                              void* d_out, int out_size, void* d_ws, size_t ws_size,
                              hipStream_t stream){
  (void)in_sizes; (void)n_in; (void)out_size;
  const void* x_in  = d_in[0];
  const int*  ei    = (const int*)d_in[1];
  const void* w_in  = d_in[2];
  const int*  yv    = (const int*)d_in[3];
  const void* W1i   = d_in[4];
  const void* b1i   = d_in[5];
  const void* Wmui  = d_in[6];
  const void* bmui  = d_in[7];
  const void* Wlvi  = d_in[8];
  const void* blvi  = d_in[9];
  const void* gmi   = d_in[10];
  const void* bti   = d_in[11];
  const int* rowA = ei;
  const int* colA = ei + NEDG;
  float* zout = (float*)d_out;

  // ---- workspace ----
  double* Dp = (double*)d_ws;
  size_t od = 0;
  double* Qd0 = Dp + od; od += (size_t)NN*RK;
  double* Qd1 = Dp + od; od += (size_t)NN*RK;
  double* Gd  = Dp + od; od += RK*RK;
  double* Rid = Dp + od; od += RK*RK;
  double* qsd = Dp + od; od += RK;
  double* sdd = Dp + od; od += RK;
  float* Fp = (float*)(Dp + od);
  size_t o = 0;
  float* xf   = Fp + o; o += (size_t)NN*INC;       // reused as h1/h2 buffer
  float* W1f  = Fp + o; o += (size_t)INC*HIDC;
  float* b1f  = Fp + o; o += HIDC;
  float* Wmuf = Fp + o; o += (size_t)HIDC*OUTC;
  float* bmuf = Fp + o; o += OUTC;
  float* Wlvf = Fp + o; o += (size_t)HIDC*OUTC;
  float* blvf = Fp + o; o += OUTC;
  float* gmf  = Fp + o; o += NDOM*HIDC;
  float* btf  = Fp + o; o += NDOM*HIDC;
  float* wf   = Fp + o; o += NEDG;
  float* xw1  = Fp + o; o += (size_t)NN*HIDC;
  float* hwA  = Fp + o; o += (size_t)NN*OUTC;
  float* hwB  = Fp + o; o += (size_t)NN*OUTC;
  float* Bf1  = Fp + o; o += (size_t)NN*RK;
  float* Cm   = Fp + o; o += (size_t)NN*RK;
  float* Qf0  = Fp + o; o += (size_t)NN*RK;
  float* Qf1  = Fp + o; o += (size_t)NN*RK;
  float* Tm   = Fp + o; o += (size_t)RK*HIDC;
  float* Umu  = Fp + o; o += 2*RK*RK;
  float* deg1 = Fp + o; o += NN;
  float* dinv1= Fp + o; o += NN;
  float* dinv2= Fp + o; o += NN;
  float* norm1= Fp + o; o += NEDG;
  float* bnsum= Fp + o; o += 8*HIDC;
  float* csrW = Fp + o; o += NEDG;
  float* cscW = Fp + o; o += NEDG;
  float* cscN = Fp + o; o += NEDG;
  ushortT* xbf   = (ushortT*)(Fp + o); o += (size_t)NN*INC/2;
  ushortT* W1bf  = (ushortT*)(Fp + o); o += (size_t)INC*HIDC/2;
  ushortT* xw1bf = (ushortT*)(Fp + o); o += (size_t)NN*HIDC/2;
  ushortT* hbf   = (ushortT*)(Fp + o); o += (size_t)NN*HIDC/2;
  ushortT* Wmubf = (ushortT*)(Fp + o); o += (size_t)HIDC*OUTC/2;
  ushortT* Wlvbf = (ushortT*)(Fp + o); o += (size_t)HIDC*OUTC/2;
  int* Ip = (int*)(Fp + o);
  size_t oi = 0;
  int* cntR = Ip + oi; oi += NN;
  int* ptrR = Ip + oi; oi += NN + 1;
  int* posR = Ip + oi; oi += NN;
  int* eidR = Ip + oi; oi += NEDG;
  int* cntC = Ip + oi; oi += NN;
  int* ptrC = Ip + oi; oi += NN + 1;
  int* posC = Ip + oi; oi += NN;
  int* eidC = Ip + oi; oi += NEDG;
  int* csrSrc = Ip + oi; oi += NEDG;
  int* cscSrc = Ip + oi; oi += NEDG;
  int* dcnt = Ip + oi; oi += NDOM;
  int* dflag= Ip + oi; oi += 1;

  size_t need = od*sizeof(double) + o*sizeof(float) + (oi+16)*sizeof(int);
  if (ws_size < need) return;

  float* hbuf = xf;  // x dead after xw1 GEMM

  const int T = 256;
  k_detect<<<1,T,0,stream>>>((const unsigned short*)x_in, dflag);
  k_upcast_all<<<cdiv(OFFT,T),T,0,stream>>>(
      x_in, W1i, w_in, Wmui, Wlvi, gmi, bti, b1i, bmui, blvi, dflag,
      xf, W1f, wf, Wmuf, Wlvf, gmf, btf, b1f, bmuf, blvf,
      xbf, W1bf, Wmubf, Wlvbf);

  k_prep<<<cdiv(NN,T),T,0,stream>>>(deg1, cntR, cntC, dcnt, bnsum);
  k_hist <<<cdiv(NEDG,T),T,0,stream>>>(rowA, colA, wf, deg1, cntR, cntC);
  k_dinv <<<cdiv(NN,T),T,0,stream>>>(deg1, dinv1, NN);
  k_norm1<<<cdiv(NEDG,T),T,0,stream>>>(rowA, colA, wf, dinv1, norm1);
  k_scan4096<<<1,1024,0,stream>>>(cntR, ptrR, posR);
  k_scan4096<<<1,1024,0,stream>>>(cntC, ptrC, posC);
  k_scatter<<<cdiv(NEDG,T),T,0,stream>>>(rowA, colA, posR, posC, eidR, eidC);
  k_edges<<<cdiv(NEDG,T),T,0,stream>>>(rowA, colA, wf, norm1, eidR, eidC,
                                       csrSrc, csrW, cscSrc, cscW, cscN);
  k_omega<<<cdiv(NN*RK,T),T,0,stream>>>(Qf0, Gd);  // f32 seed + Gd zero
  k_dcnt <<<cdiv(NN,T),T,0,stream>>>(yv, dcnt);

  // ---- branch-1 head ----
  k_gemm_bf16<<<dim3(HIDC/64, NN/64),256,0,stream>>>(xbf, W1bf, xw1, xw1bf);

  // ---- branch-2 subspace chain up to Gram (64-thread blocks, r25-proven) ----
  k_spmm32<<<NN,64,0,stream>>>(ptrR, csrSrc, csrW, Qf0, Qf1);       // P1
  k_spmm32<<<NN,64,0,stream>>>(ptrC, cscSrc, cscW, Qf1, Qf0);       // P2
  k_spmm32<<<NN,64,0,stream>>>(ptrR, csrSrc, csrW, Qf0, Qf1);       // P3
  k_spmm32<<<NN,64,0,stream>>>(ptrC, cscSrc, cscW, Qf1, Qf0);       // P4
  k_spmm32to64<<<NN,64,0,stream>>>(ptrR, csrSrc, csrW, Qf0, Qd1);   // P5 (f64)
  k_gram64<<<NN/64,256,0,stream>>>(Qd1, Gd);

  // ---- FUSED: chol | h1 spmm ----
  k_chol_spmm<<<NN+1,256,0,stream>>>(Gd, sdd, ptrC, cscSrc, cscN, xw1bf, hbuf,
                                     dinv1, b1f);
  // ---- FUSED: trinv | bnpart(h1) ----
  k_trinv_bn<<<1+NN/32,256,0,stream>>>(Gd, sdd, Rid, hbuf, yv, bnsum);
  // ---- FUSED: applyR (+Bf1) | bnapply(h1) ----
  k_applyR_bn<<<NN/4 + cdiv(NN*HIDC,T),256,0,stream>>>(Qd1, Rid, Qd0, Bf1,
      hbuf, yv, bnsum, dcnt, gmf, btf, hbf);
  // ---- FUSED: qsum | spmmC-f32 | gemm_hw2(h1) ----
  k_qsum_spmmC_hw2<<<64 + NN/4 + 2*(NN/64),256,0,stream>>>(Qd0, qsd,
      ptrC, cscSrc, cscW, Bf1, Cm, hbf, Wmubf, Wlvbf, hwA, hwB);
  // ---- FUSED: fin-chores | output spmm2(h1) ----
  k_fin_spmm2<<<128 + 2*(NN/4),256,0,stream>>>(Cm, qsd, dinv2, Tm, Umu, bnsum,
      ptrC, cscSrc, cscN, hwA, hwB, zout, dinv1, bmuf, blvf);

  // ---- branch-2 tail ----
  k_gemm_tn_sk<<<dim3(HIDC/16, RK/16, 8),256,0,stream>>>(RK,HIDC,NN,512, Bf1,RK, xw1,HIDC, Tm,HIDC, dinv2);
  k_gemm_nn<<<dim3(HIDC/64, NN/64),256,0,stream>>>(NN,HIDC,RK, Cm,RK, Tm,HIDC, hbuf,HIDC, dinv2, nullptr, b1f);
  k_bnpart<<<NN/32,256,0,stream>>>(hbuf, yv, bnsum);
  k_bnapply<<<cdiv(NN*HIDC,T),T,0,stream>>>(hbuf, yv, bnsum, dcnt, gmf, btf, hbf);
  k_gemm_hw2<<<2*(NN/64),256,0,stream>>>(hbf, Wmubf, Wlvbf, hwA, hwB);
  k_gemm_tn_sk2<<<dim3(RK/16, RK/16, 32),256,0,stream>>>(Bf1, hwA, hwB, Umu, dinv2);
  k_gemm_nn2<<<dim3(1, NN/64, 2),256,0,stream>>>(Cm, Umu, dinv2, bmuf, blvf, zout);
}

// Round 15
// 530.226 us; speedup vs baseline: 1.0833x; 1.0429x over previous
//
#include <hip/hip_runtime.h>
#include <hip/hip_bf16.h>

// GCNEncoder — r30: dead-store elimination + last long-K f32 GEMM -> MFMA.
// (a) bnapply's f32 H store is DEAD in both uses (only hbf read after;
//     h2's hbuf rewritten by gemm_nn before bnpart) -> drop, -16MB writes.
// (b) Tm GEMM (64x512x4096 split-K f32 SIMT) -> bf16 MFMA (r22 pattern):
//     A = bf16(dinv2*Qb) converted on-the-fly in staging (Bf1+dinv2 ready
//     post-fin), B = xw1bf, f32 atomicAdd into pre-zeroed Tm.
// (c) xw1 f32 now dead -> gemm_bf16 drops its 8MB f32 store.
// absmax may tick to <=~0.012 (one new bf16 rounding on Qb side; thr .0317).
// History: r29 553; r27 556; r26 578; r25 650; r22 836; r16 1138.

#define NN    4096
#define NEDG  131072
#define INC   512
#define HIDC  512
#define OUTC  64
#define RK    64
#define NDOM  4
#define EPSBN 1e-5f

typedef unsigned short ushortT;
typedef __attribute__((ext_vector_type(8))) short bf16x8;
typedef __attribute__((ext_vector_type(4))) float f32x4;

static inline int cdiv(int a, int b){ return (a + b - 1) / b; }

__device__ __forceinline__ float bf2f(unsigned u){ return __uint_as_float(u << 16); }

// ---------------- input dtype detection ----------------
__global__ __launch_bounds__(256) void k_detect(const unsigned short* __restrict__ p,
                                                int* __restrict__ flag){
  int t = threadIdx.x;
  int cnt = 0;
  for (int i = t; i < 4096; i += 256){
    unsigned short v = p[2*i];
    int e = (v >> 7) & 0xFF;
    if (e >= 100 && e <= 140) cnt++;
  }
  __shared__ int sh[256];
  sh[t] = cnt; __syncthreads();
  for (int off = 128; off > 0; off >>= 1){ if (t < off) sh[t] += sh[t+off]; __syncthreads(); }
  if (t == 0) *flag = (sh[0] >= 2048) ? 0 : 1;
}

// ---------------- fused upcast ----------------
__device__ __forceinline__ float upc1(const void* s, int f, int off){
  return f ? ((const float*)s)[off]
           : __bfloat162float(((const __hip_bfloat16*)s)[off]);
}
__device__ __forceinline__ ushortT tobf(float v){
  __hip_bfloat16 h = __float2bfloat16(v);
  return *(ushortT*)&h;
}
#define SEG_X   2097152
#define SEG_W1  262144
#define SEG_W   131072
#define SEG_WMU 32768
#define SEG_GB  2048
#define SEG_B1  512
#define SEG_BO  64
#define OFF1 (SEG_X)
#define OFF2 (OFF1+SEG_W1)
#define OFF3 (OFF2+SEG_W)
#define OFF4 (OFF3+SEG_WMU)
#define OFF5 (OFF4+SEG_WMU)
#define OFF6 (OFF5+SEG_GB)
#define OFF7 (OFF6+SEG_GB)
#define OFF8 (OFF7+SEG_B1)
#define OFF9 (OFF8+SEG_BO)
#define OFFT (OFF9+SEG_BO)

__global__ __launch_bounds__(256) void k_upcast_all(
    const void* x, const void* W1, const void* w, const void* Wmu, const void* Wlv,
    const void* gm, const void* bt, const void* b1, const void* bmu, const void* blv,
    const int* __restrict__ isf32,
    float* dx, float* dW1, float* dw, float* dWmu, float* dWlv,
    float* dgm, float* dbt, float* db1, float* dbmu, float* dblv,
    ushortT* xbf, ushortT* W1bf, ushortT* Wmubf, ushortT* Wlvbf){
  int i = blockIdx.x*256 + threadIdx.x;
  if (i >= OFFT) return;
  int f = *isf32;
  if      (i < OFF1){ float v = upc1(x, f, i); dx[i] = v; xbf[i] = tobf(v); }
  else if (i < OFF2){ float v = upc1(W1, f, i - OFF1); dW1[i - OFF1] = v; W1bf[i - OFF1] = tobf(v); }
  else if (i < OFF3) dw  [i - OFF2] = upc1(w,   f, i - OFF2);
  else if (i < OFF4){ float v = upc1(Wmu, f, i - OFF3); dWmu[i - OFF3] = v; Wmubf[i - OFF3] = tobf(v); }
  else if (i < OFF5){ float v = upc1(Wlv, f, i - OFF4); dWlv[i - OFF4] = v; Wlvbf[i - OFF4] = tobf(v); }
  else if (i < OFF6) dgm [i - OFF5] = upc1(gm,  f, i - OFF5);
  else if (i < OFF7) dbt [i - OFF6] = upc1(bt,  f, i - OFF6);
  else if (i < OFF8) db1 [i - OFF7] = upc1(b1,  f, i - OFF7);
  else if (i < OFF9) dbmu[i - OFF8] = upc1(bmu, f, i - OFF8);
  else               dblv[i - OFF9] = upc1(blv, f, i - OFF9);
}

// ---------------- small utils ----------------
__global__ __launch_bounds__(256) void k_prep(float* deg, int* cntR, int* cntC, int* dcnt,
                                              float* bnsum){
  int i = blockIdx.x*256 + threadIdx.x;
  if (i < NN){ deg[i] = 1.0f; cntR[i] = 0; cntC[i] = 0; }
  if (i < NDOM) dcnt[i] = 0;
  if (i < 8*HIDC) bnsum[i] = 0.f;
}

// ---------------- graph preprocessing ----------------
__global__ __launch_bounds__(256) void k_hist(const int* __restrict__ row, const int* __restrict__ col,
                                              const float* __restrict__ w, float* deg,
                                              int* cntR, int* cntC){
  int e = blockIdx.x*256 + threadIdx.x;
  if (e < NEDG){
    atomicAdd(&deg[col[e]], w[e]);
    atomicAdd(&cntR[row[e]], 1);
    atomicAdd(&cntC[col[e]], 1);
  }
}
__global__ __launch_bounds__(256) void k_dinv(const float* deg, float* dinv, int n){
  int i = blockIdx.x*256 + threadIdx.x;
  if (i < n){ float d = deg[i]; dinv[i] = (d > 0.f) ? 1.f/sqrtf(d) : 0.f; }
}
__global__ __launch_bounds__(256) void k_norm1(const int* __restrict__ row, const int* __restrict__ col,
                                               const float* __restrict__ w, const float* __restrict__ dinv,
                                               float* __restrict__ nrm){
  int e = blockIdx.x*256 + threadIdx.x;
  if (e < NEDG) nrm[e] = dinv[row[e]] * w[e] * dinv[col[e]];
}
__global__ __launch_bounds__(1024) void k_scan4096(const int* __restrict__ cnt,
                                                   int* __restrict__ ptr, int* __restrict__ pos){
  __shared__ int sh[1024];
  int t = threadIdx.x;
  int b = t*4;
  int a0 = cnt[b], a1 = cnt[b+1], a2 = cnt[b+2], a3 = cnt[b+3];
  sh[t] = a0 + a1 + a2 + a3;
  __syncthreads();
  for (int off = 1; off < 1024; off <<= 1){
    int v = (t >= off) ? sh[t-off] : 0;
    __syncthreads();
    sh[t] += v;
    __syncthreads();
  }
  int excl = (t == 0) ? 0 : sh[t-1];
  ptr[b]   = excl;            pos[b]   = excl;
  ptr[b+1] = excl+a0;         pos[b+1] = excl+a0;
  ptr[b+2] = excl+a0+a1;      pos[b+2] = excl+a0+a1;
  ptr[b+3] = excl+a0+a1+a2;   pos[b+3] = excl+a0+a1+a2;
  if (t == 1023) ptr[4096] = sh[1023];
}
__global__ __launch_bounds__(256) void k_scatter(const int* __restrict__ row, const int* __restrict__ col,
                                                 int* posR, int* posC, int* eidR, int* eidC){
  int e = blockIdx.x*256 + threadIdx.x;
  if (e < NEDG){
    int p = atomicAdd(&posR[row[e]], 1); eidR[p] = e;
    int q = atomicAdd(&posC[col[e]], 1); eidC[q] = e;
  }
}
__global__ __launch_bounds__(256) void k_edges(const int* __restrict__ rowA, const int* __restrict__ colA,
        const float* __restrict__ wf, const float* __restrict__ nrm,
        const int* __restrict__ eidR, const int* __restrict__ eidC,
        int* __restrict__ csrSrc, float* __restrict__ csrW,
        int* __restrict__ cscSrc, float* __restrict__ cscW, float* __restrict__ cscN){
  int p = blockIdx.x*256 + threadIdx.x;
  if (p < NEDG){
    int eR = eidR[p]; csrSrc[p] = colA[eR]; csrW[p] = wf[eR];
    int eC = eidC[p]; cscSrc[p] = rowA[eC]; cscW[p] = wf[eC]; cscN[p] = nrm[eC];
  }
}
__global__ __launch_bounds__(256) void k_dcnt(const int* __restrict__ y, int* dcnt){
  int i = blockIdx.x*256 + threadIdx.x;
  if (i < NN) atomicAdd(&dcnt[y[i]], 1);
}

// ---------------- threefry2x32 (KAT-verified) ----------------
__device__ __forceinline__ unsigned rotl32(unsigned x, unsigned d){ return (x << d) | (x >> (32u - d)); }
#define TF_ROUND4(R0,R1,R2,R3) \
  x0 += x1; x1 = rotl32(x1,R0); x1 ^= x0; \
  x0 += x1; x1 = rotl32(x1,R1); x1 ^= x0; \
  x0 += x1; x1 = rotl32(x1,R2); x1 ^= x0; \
  x0 += x1; x1 = rotl32(x1,R3); x1 ^= x0;

__device__ __forceinline__ void tf2x32(unsigned k0, unsigned k1, unsigned c0, unsigned c1,
                                       unsigned* o0, unsigned* o1){
  unsigned ks2 = 0x1BD11BDAu ^ k0 ^ k1;
  unsigned x0 = c0 + k0, x1 = c1 + k1;
  TF_ROUND4(13,15,26,6);   x0 += k1;  x1 += ks2 + 1u;
  TF_ROUND4(17,29,16,24);  x0 += ks2; x1 += k0 + 2u;
  TF_ROUND4(13,15,26,6);   x0 += k0;  x1 += k1 + 3u;
  TF_ROUND4(17,29,16,24);  x0 += k1;  x1 += ks2 + 4u;
  TF_ROUND4(13,15,26,6);   x0 += ks2; x1 += k0 + 5u;
  *o0 = x0; *o1 = x1;
}

// ---------------- omega (verified; f32 out; + Gd zero fold) ----------------
__device__ double erfinv64(double x){
  double w = -log1p(-x*x);
  double p;
  if (w < 5.0){
    w -= 2.5;
    p = 2.81022636e-08;  p = p*w + 3.43273939e-07; p = p*w - 3.5233877e-06;
    p = p*w - 4.39150654e-06; p = p*w + 0.00021858087; p = p*w - 0.00125372503;
    p = p*w - 0.00417768164;  p = p*w + 0.246640727;   p = p*w + 1.50140941;
  } else {
    w = sqrt(w) - 3.0;
    p = -0.000200214257; p = p*w + 0.000100950558; p = p*w + 0.00134934322;
    p = p*w - 0.00367342844; p = p*w + 0.00573950773; p = p*w - 0.0076224613;
    p = p*w + 0.00943887047; p = p*w + 1.00167406;    p = p*w + 2.83297682;
  }
  double y = p * x;
  const double c = 1.1283791670955126;   // 2/sqrt(pi)
  #pragma unroll
  for (int it = 0; it < 3; it++){
    double err = erf(y) - x;
    y -= err / (c * exp(-y*y));
  }
  return y;
}

__device__ float bits_to_normal(unsigned b){
  float f = __uint_as_float((b >> 9) | 0x3f800000u) - 1.0f;
  const float lo = -0.99999994f;
  float x = fmaxf(lo, f * 2.0f + lo);
  double r = 1.4142135623730951 * erfinv64((double)x);
  return (float)r;
}

__global__ __launch_bounds__(256) void k_omega(float* __restrict__ om, double* __restrict__ Gd){
  int i = blockIdx.x*256 + threadIdx.x;
  if (i < RK*RK) Gd[i] = 0.0;
  if (i >= 262144) return;
  unsigned o0, o1;
  tf2x32(0u, 42u, 0u, (unsigned)i, &o0, &o1);
  om[i] = bits_to_normal(o0 ^ o1);
}

// ---------------- bf16 MFMA GEMM (r22-proven; r30: bf16-only output) ----------------
__global__ __launch_bounds__(256) void k_gemm_bf16(
    const ushortT* __restrict__ A, const ushortT* __restrict__ B,
    ushortT* __restrict__ Cbf){
  __shared__ ushortT As2[64][40];
  __shared__ ushortT Bs2[64][40];
  int t = threadIdx.x;
  int bm = blockIdx.y * 64, bn = blockIdx.x * 64;
  int w = t >> 6, l = t & 63;
  int lr = l & 15, lk = l >> 4;
  f32x4 acc[4] = {};
  int ar = t >> 2, ac = (t & 3) * 8;
  int bc = t & 63, bk = (t >> 6) * 8;
  for (int k0 = 0; k0 < 512; k0 += 32){
    *(uint4*)&As2[ar][ac] = *(const uint4*)&A[(size_t)(bm + ar) * 512 + k0 + ac];
    ushortT tmp[8];
    #pragma unroll
    for (int j = 0; j < 8; j++)
      tmp[j] = B[(size_t)(k0 + bk + j) * 512 + bn + bc];
    *(uint4*)&Bs2[bc][bk] = *(uint4*)tmp;
    __syncthreads();
    bf16x8 afrag = *(bf16x8*)&As2[w * 16 + lr][lk * 8];
    #pragma unroll
    for (int nt = 0; nt < 4; nt++){
      bf16x8 bfrag = *(bf16x8*)&Bs2[nt * 16 + lr][lk * 8];
      acc[nt] = __builtin_amdgcn_mfma_f32_16x16x32_bf16(afrag, bfrag, acc[nt], 0, 0, 0);
    }
    __syncthreads();
  }
  #pragma unroll
  for (int nt = 0; nt < 4; nt++){
    #pragma unroll
    for (int i = 0; i < 4; i++){
      size_t idx = (size_t)(bm + w * 16 + lk * 4 + i) * 512 + bn + nt * 16 + lr;
      Cbf[idx] = tobf(acc[nt][i]);
    }
  }
}

// device body: paired hw GEMM
__device__ __forceinline__ void d_hw2(int bx, int t,
    const ushortT* __restrict__ A, const ushortT* __restrict__ Bm,
    const ushortT* __restrict__ Bl, float* __restrict__ Ca, float* __restrict__ Cb){
  __shared__ ushortT As2[64][40];
  __shared__ ushortT Bs2[64][40];
  int nb = NN/64;
  int second = bx >= nb;
  int bm = (bx - (second ? nb : 0)) * 64;
  const ushortT* B = second ? Bl : Bm;
  float* Cc = second ? Cb : Ca;
  int w = t >> 6, l = t & 63;
  int lr = l & 15, lk = l >> 4;
  f32x4 acc[4] = {};
  int ar = t >> 2, ac = (t & 3) * 8;
  int bc = t & 63, bk = (t >> 6) * 8;
  for (int k0 = 0; k0 < 512; k0 += 32){
    *(uint4*)&As2[ar][ac] = *(const uint4*)&A[(size_t)(bm + ar) * 512 + k0 + ac];
    ushortT tmp[8];
    #pragma unroll
    for (int j = 0; j < 8; j++)
      tmp[j] = B[(size_t)(k0 + bk + j) * 64 + bc];
    *(uint4*)&Bs2[bc][bk] = *(uint4*)tmp;
    __syncthreads();
    bf16x8 afrag = *(bf16x8*)&As2[w * 16 + lr][lk * 8];
    #pragma unroll
    for (int nt = 0; nt < 4; nt++){
      bf16x8 bfrag = *(bf16x8*)&Bs2[nt * 16 + lr][lk * 8];
      acc[nt] = __builtin_amdgcn_mfma_f32_16x16x32_bf16(afrag, bfrag, acc[nt], 0, 0, 0);
    }
    __syncthreads();
  }
  #pragma unroll
  for (int nt = 0; nt < 4; nt++){
    #pragma unroll
    for (int i = 0; i < 4; i++){
      Cc[(size_t)(bm + w * 16 + lk * 4 + i) * 64 + nt * 16 + lr] = acc[nt][i];
    }
  }
}
__global__ __launch_bounds__(256) void k_gemm_hw2(
    const ushortT* __restrict__ A, const ushortT* __restrict__ Bm,
    const ushortT* __restrict__ Bl, float* __restrict__ Ca, float* __restrict__ Cb){
  d_hw2(blockIdx.x, threadIdx.x, A, Bm, Bl, Ca, Cb);
}

// ---------------- GEMM (fp32, h2 dense) ----------------
__global__ __launch_bounds__(256) void k_gemm_nn(int M, int Nn, int K,
      const float* __restrict__ A, int lda, const float* __restrict__ B, int ldb,
      float* __restrict__ Cc, int ldc, const float* __restrict__ rowscale,
      const float* __restrict__ kscale, const float* __restrict__ bias){
  __shared__ float As[16][65];
  __shared__ float Bs[16][65];
  int bm = blockIdx.y*64, bn = blockIdx.x*64;
  int t = threadIdx.x;
  int tr = t >> 4, tc = t & 15;
  float acc[4][4] = {};
  for (int k0 = 0; k0 < K; k0 += 16){
    #pragma unroll
    for (int q = 0; q < 4; q++){
      int idx = t*4 + q;
      int m = idx >> 4, kk = idx & 15;
      As[kk][m] = A[(size_t)(bm+m)*lda + (k0+kk)];
    }
    #pragma unroll
    for (int q = 0; q < 4; q++){
      int idx = t + q*256;
      int kk = idx >> 6, n = idx & 63;
      float ks = kscale ? kscale[k0+kk] : 1.0f;
      Bs[kk][n] = B[(size_t)(k0+kk)*ldb + (bn+n)] * ks;
    }
    __syncthreads();
    #pragma unroll
    for (int kk = 0; kk < 16; kk++){
      float a0 = As[kk][tr*4+0], a1 = As[kk][tr*4+1], a2 = As[kk][tr*4+2], a3 = As[kk][tr*4+3];
      float b0 = Bs[kk][tc*4+0], b1 = Bs[kk][tc*4+1], b2 = Bs[kk][tc*4+2], b3 = Bs[kk][tc*4+3];
      acc[0][0] += a0*b0; acc[0][1] += a0*b1; acc[0][2] += a0*b2; acc[0][3] += a0*b3;
      acc[1][0] += a1*b0; acc[1][1] += a1*b1; acc[1][2] += a1*b2; acc[1][3] += a1*b3;
      acc[2][0] += a2*b0; acc[2][1] += a2*b1; acc[2][2] += a2*b2; acc[2][3] += a2*b3;
      acc[3][0] += a3*b0; acc[3][1] += a3*b1; acc[3][2] += a3*b2; acc[3][3] += a3*b3;
    }
    __syncthreads();
  }
  #pragma unroll
  for (int i2 = 0; i2 < 4; i2++){
    int m = bm + tr*4 + i2;
    float rs = rowscale ? rowscale[m] : 1.0f;
    #pragma unroll
    for (int j2 = 0; j2 < 4; j2++){
      int n = bn + tc*4 + j2;
      float v = acc[i2][j2] * rs;
      if (bias) v += bias[n];
      Cc[(size_t)m*ldc + n] = v;
    }
  }
}

// paired zout2/zout3 GEMMs
__global__ __launch_bounds__(256) void k_gemm_nn2(
      const float* __restrict__ A, const float* __restrict__ Um,
      const float* __restrict__ rowscale,
      const float* __restrict__ bmu, const float* __restrict__ blv,
      float* __restrict__ zout){
  __shared__ float As[16][65];
  __shared__ float Bs[16][65];
  int z = blockIdx.z;
  const float* B = Um + (size_t)z*RK*RK;
  const float* bias = z ? blv : bmu;
  float* Cc = zout + (size_t)(2+z)*NN*OUTC;
  int bm = blockIdx.y*64;
  int t = threadIdx.x;
  int tr = t >> 4, tc = t & 15;
  float acc[4][4] = {};
  for (int k0 = 0; k0 < RK; k0 += 16){
    #pragma unroll
    for (int q = 0; q < 4; q++){
      int idx = t*4 + q;
      int m = idx >> 4, kk = idx & 15;
      As[kk][m] = A[(size_t)(bm+m)*RK + (k0+kk)];
    }
    #pragma unroll
    for (int q = 0; q < 4; q++){
      int idx = t + q*256;
      int kk = idx >> 6, n = idx & 63;
      Bs[kk][n] = B[(size_t)(k0+kk)*RK + n];
    }
    __syncthreads();
    #pragma unroll
    for (int kk = 0; kk < 16; kk++){
      float a0 = As[kk][tr*4+0], a1 = As[kk][tr*4+1], a2 = As[kk][tr*4+2], a3 = As[kk][tr*4+3];
      float b0 = Bs[kk][tc*4+0], b1 = Bs[kk][tc*4+1], b2 = Bs[kk][tc*4+2], b3 = Bs[kk][tc*4+3];
      acc[0][0] += a0*b0; acc[0][1] += a0*b1; acc[0][2] += a0*b2; acc[0][3] += a0*b3;
      acc[1][0] += a1*b0; acc[1][1] += a1*b1; acc[1][2] += a1*b2; acc[1][3] += a1*b3;
      acc[2][0] += a2*b0; acc[2][1] += a2*b1; acc[2][2] += a2*b2; acc[2][3] += a2*b3;
      acc[3][0] += a3*b0; acc[3][1] += a3*b1; acc[3][2] += a3*b2; acc[3][3] += a3*b3;
    }
    __syncthreads();
  }
  #pragma unroll
  for (int i2 = 0; i2 < 4; i2++){
    int m = bm + tr*4 + i2;
    float rs = rowscale[m];
    #pragma unroll
    for (int j2 = 0; j2 < 4; j2++){
      int n = tc*4 + j2;
      Cc[(size_t)m*OUTC + n] = acc[i2][j2] * rs + bias[n];
    }
  }
}

// ---- Tm GEMM via bf16 MFMA (r30): Tm[64][512] = (D Qb)^T_bf16 @ xw1bf.
// grid (HIDC/64=8 n-tiles, 8 k-chunks of 512); A converted on the fly:
// A[m][k] = bf16(dinv2[k] * Bf1[k*64+m]); f32 atomicAdd into pre-zeroed Tm.
// Fragment mapping identical to k_gemm_bf16/d_hw2 (r22-proven).
__global__ __launch_bounds__(256) void k_gemm_tn_bfm(
    const float* __restrict__ Bf1, const float* __restrict__ dinv2,
    const ushortT* __restrict__ xw1bf, float* __restrict__ Tm){
  __shared__ ushortT As2[64][40];   // [m][k]
  __shared__ ushortT Bs2[64][40];   // [n][k]
  int t = threadIdx.x;
  int bn = blockIdx.x * 64;
  int kb = blockIdx.y * 512;
  int w = t >> 6, l = t & 63;
  int lr = l & 15, lk = l >> 4;
  f32x4 acc[4] = {};
  int sc = t & 63, sk = (t >> 6) * 8;   // col sc, k-rows sk..sk+7
  for (int k0 = kb; k0 < kb + 512; k0 += 32){
    ushortT tmpA[8], tmpB[8];
    #pragma unroll
    for (int j = 0; j < 8; j++){
      int krow = k0 + sk + j;
      tmpA[j] = tobf(dinv2[krow] * Bf1[(size_t)krow*RK + sc]);
      tmpB[j] = xw1bf[(size_t)krow*HIDC + bn + sc];
    }
    *(uint4*)&As2[sc][sk] = *(uint4*)tmpA;
    *(uint4*)&Bs2[sc][sk] = *(uint4*)tmpB;
    __syncthreads();
    bf16x8 afrag = *(bf16x8*)&As2[w*16 + lr][lk*8];
    #pragma unroll
    for (int nt = 0; nt < 4; nt++){
      bf16x8 bfrag = *(bf16x8*)&Bs2[nt*16 + lr][lk*8];
      acc[nt] = __builtin_amdgcn_mfma_f32_16x16x32_bf16(afrag, bfrag, acc[nt], 0, 0, 0);
    }
    __syncthreads();
  }
  #pragma unroll
  for (int nt = 0; nt < 4; nt++){
    #pragma unroll
    for (int i = 0; i < 4; i++){
      atomicAdd(&Tm[(size_t)(w*16 + lk*4 + i)*HIDC + bn + nt*16 + lr], acc[nt][i]);
    }
  }
}

// paired Umu/Ulv split-K TN
__global__ __launch_bounds__(256) void k_gemm_tn_sk2(
      const float* __restrict__ A,
      const float* __restrict__ Ba, const float* __restrict__ Bb,
      float* __restrict__ Um, const float* __restrict__ kscale){
  __shared__ float As[32][17];
  __shared__ float Bs[32][17];
  int z = blockIdx.z;
  int second = z >= 16;
  int kb = (second ? z - 16 : z) * 256, ke = kb + 256;
  const float* B = second ? Bb : Ba;
  float* Cc = Um + (second ? RK*RK : 0);
  int bm = blockIdx.y*16, bn = blockIdx.x*16;
  int t = threadIdx.x;
  int tm = t >> 4, tn = t & 15;
  float acc = 0.f;
  for (int k0 = kb; k0 < ke; k0 += 32){
    #pragma unroll
    for (int q = 0; q < 2; q++){
      int idx = t + q*256;
      int kk = idx >> 4, m = idx & 15;
      As[kk][m] = A[(size_t)(k0+kk)*RK + (bm+m)] * kscale[k0+kk];
      Bs[kk][m] = B[(size_t)(k0+kk)*OUTC + (bn+m)];
    }
    __syncthreads();
    #pragma unroll
    for (int kk = 0; kk < 32; kk++) acc += As[kk][tm] * Bs[kk][tn];
    __syncthreads();
  }
  atomicAdd(&Cc[(size_t)(bm+tm)*RK + (bn+tn)], acc);
}

// ---------------- subspace chain SpMMs (r25-proven 64-thread blocks) ----------------
__global__ __launch_bounds__(64) void k_spmm32(const int* __restrict__ ptr,
                       const int* __restrict__ src, const float* __restrict__ cf,
                       const float* __restrict__ X, float* __restrict__ Y){
  int seg = blockIdx.x;
  int t = threadIdx.x;
  double acc = 0.0;
  int p0 = ptr[seg], p1 = ptr[seg+1];
  for (int p = p0; p < p1; ++p){
    acc += (double)cf[p] * (double)X[(size_t)src[p]*RK + t];
  }
  Y[(size_t)seg*RK + t] = (float)acc;
}
__global__ __launch_bounds__(64) void k_spmm32to64(const int* __restrict__ ptr,
                       const int* __restrict__ src, const float* __restrict__ cf,
                       const float* __restrict__ X, double* __restrict__ Y){
  int seg = blockIdx.x;
  int t = threadIdx.x;
  double acc = 0.0;
  int p0 = ptr[seg], p1 = ptr[seg+1];
  for (int p = p0; p < p1; ++p){
    acc += (double)cf[p] * (double)X[(size_t)src[p]*RK + t];
  }
  Y[(size_t)seg*RK + t] = acc;
}
// Gram: G += Xslice^T Xslice
__global__ __launch_bounds__(256) void k_gram64(const double* __restrict__ X, double* __restrict__ G){
  __shared__ double Xs[64][65];
  int b = blockIdx.x;
  int t = threadIdx.x;
  #pragma unroll
  for (int q = 0; q < 16; q++){
    int idx = t + q*256;
    Xs[idx >> 6][idx & 63] = X[(size_t)(b*64 + (idx >> 6))*RK + (idx & 63)];
  }
  __syncthreads();
  int i = t >> 2;
  int j0 = (t & 3) * 16;
  double acc[16];
  #pragma unroll
  for (int jj = 0; jj < 16; jj++) acc[jj] = 0.0;
  for (int k = 0; k < 64; k++){
    double a = Xs[k][i];
    #pragma unroll
    for (int jj = 0; jj < 16; jj++) acc[jj] += a * Xs[k][j0+jj];
  }
  #pragma unroll
  for (int jj = 0; jj < 16; jj++) atomicAdd(&G[i*RK + j0 + jj], acc[jj]);
}

// ---- FUSED: block0 = Cholesky v1 (r26-proven); blocks 1..NN = h1 spmm ----
#define CHOLF_CHUNK(I0) \
  for (int k2 = 0; k2 < 16; k2++){ \
    int k = (I0) + k2; \
    int buf = k & 1; \
    if (t < 64 && j == k){ \
      double d = sqrt(fmax(cdiag, 1e-300)); \
      double s = 1.0 / d; \
      myd = d; \
      sdd[k] = s; \
      _Pragma("unroll") \
      for (int i = (I0); i < 64; i++){ c[i] *= s; colk[buf][i] = c[i]; } \
    } \
    __syncthreads(); \
    if (t < 64 && j > k && j < 64){ \
      double cj = colk[buf][j]; \
      cdiag -= cj * cj; \
      _Pragma("unroll") \
      for (int i = (I0); i < 64; i++){ c[i] -= colk[buf][i] * cj; } \
    } \
    __syncthreads(); \
  }

__global__ __launch_bounds__(256) void k_chol_spmm(
    double* __restrict__ G, double* __restrict__ sdd,
    const int* __restrict__ ptr, const int* __restrict__ src, const float* __restrict__ cf,
    const ushortT* __restrict__ Xb, float* __restrict__ Y,
    const float* __restrict__ self_dinv, const float* __restrict__ bias){
  __shared__ double colk[2][64];
  int t = threadIdx.x;
  if (blockIdx.x == 0){
    int j = t;
    double c[64];
    double cdiag = 0.0, myd = 0.0;
    if (t < 64){
      #pragma unroll
      for (int i = 0; i < 64; i++) c[i] = G[i*64 + j];
      #pragma unroll
      for (int i = 0; i < 64; i++) if (i == j) cdiag = c[i];
    }
    CHOLF_CHUNK(0)
    CHOLF_CHUNK(16)
    CHOLF_CHUNK(32)
    CHOLF_CHUNK(48)
    if (t < 64){
      #pragma unroll
      for (int i = 0; i < 64; i++){
        double v = (i > j) ? c[i] : 0.0;
        if (i == j) v = myd;
        G[i*64 + j] = v;
      }
    }
  } else {
    int seg = blockIdx.x - 1;
    float acc0, acc1;
    {
      float sd = self_dinv[seg]; float s2 = sd*sd;
      unsigned v = *(const unsigned*)&Xb[(size_t)seg*HIDC + 2*t];
      acc0 = s2 * bf2f(v & 0xffffu);
      acc1 = s2 * bf2f(v >> 16);
    }
    int p0 = ptr[seg], p1 = ptr[seg+1];
    for (int p = p0; p < p1; ++p){
      int o = src[p];
      float cc = cf[p];
      unsigned v = *(const unsigned*)&Xb[(size_t)o*HIDC + 2*t];
      acc0 += cc * bf2f(v & 0xffffu);
      acc1 += cc * bf2f(v >> 16);
    }
    acc0 += bias[2*t];
    acc1 += bias[2*t+1];
    Y[(size_t)seg*HIDC + 2*t]     = acc0;
    Y[(size_t)seg*HIDC + 2*t + 1] = acc1;
  }
}

// ---- BN partials (coalesced, r27-proven) ----
__device__ __forceinline__ void d_bnpart(int b, int t,
    const float* __restrict__ H, const int* __restrict__ y, float* __restrict__ bnsum){
  int j0 = 2*t;
  float s00=0,s01=0,s10=0,s11=0,s20=0,s21=0,s30=0,s31=0;
  float q00=0,q01=0,q10=0,q11=0,q20=0,q21=0,q30=0,q31=0;
  int r0 = b*32;
  for (int r = r0; r < r0+32; r++){
    int d = y[r];
    float2 v = *(const float2*)&H[(size_t)r*HIDC + j0];
    float ax = v.x, ay = v.y;
    float bx = ax*ax, by = ay*ay;
    if      (d == 0){ s00+=ax; s01+=ay; q00+=bx; q01+=by; }
    else if (d == 1){ s10+=ax; s11+=ay; q10+=bx; q11+=by; }
    else if (d == 2){ s20+=ax; s21+=ay; q20+=bx; q21+=by; }
    else            { s30+=ax; s31+=ay; q30+=bx; q31+=by; }
  }
  atomicAdd(&bnsum[0*HIDC+j0], s00); atomicAdd(&bnsum[0*HIDC+j0+1], s01);
  atomicAdd(&bnsum[1*HIDC+j0], s10); atomicAdd(&bnsum[1*HIDC+j0+1], s11);
  atomicAdd(&bnsum[2*HIDC+j0], s20); atomicAdd(&bnsum[2*HIDC+j0+1], s21);
  atomicAdd(&bnsum[3*HIDC+j0], s30); atomicAdd(&bnsum[3*HIDC+j0+1], s31);
  atomicAdd(&bnsum[4*HIDC+j0], q00); atomicAdd(&bnsum[4*HIDC+j0+1], q01);
  atomicAdd(&bnsum[5*HIDC+j0], q10); atomicAdd(&bnsum[5*HIDC+j0+1], q11);
  atomicAdd(&bnsum[6*HIDC+j0], q20); atomicAdd(&bnsum[6*HIDC+j0+1], q21);
  atomicAdd(&bnsum[7*HIDC+j0], q30); atomicAdd(&bnsum[7*HIDC+j0+1], q31);
}
__global__ __launch_bounds__(256) void k_bnpart(const float* __restrict__ H,
        const int* __restrict__ y, float* __restrict__ bnsum){
  d_bnpart(blockIdx.x, threadIdx.x, H, y, bnsum);
}

// ---- BN apply, bf16-only output (r30: f32 H store was dead) ----
__device__ __forceinline__ void d_bnapply(int idx,
    const float* __restrict__ H, const int* __restrict__ y,
    const float* __restrict__ bnsum, const int* __restrict__ dcnt,
    const float* __restrict__ gamma, const float* __restrict__ beta,
    ushortT* __restrict__ Hbf){
  int n = idx >> 9, j = idx & (HIDC-1);
  int d = y[n];
  float cnt  = fmaxf((float)dcnt[d], 1.0f);
  float mean = bnsum[d*HIDC + j] / cnt;
  float var  = fmaxf(bnsum[(4+d)*HIDC + j] / cnt - mean*mean, 0.f);
  float inv  = 1.0f / sqrtf(var + EPSBN);
  float gmm  = gamma[d*HIDC + j];
  float scal = gmm * inv;
  float shft = beta[d*HIDC + j] - mean * gmm * inv;
  float v = H[idx] * scal + shft;
  v = v > 0.f ? v : 0.f;
  Hbf[idx] = tobf(v);
}
__global__ __launch_bounds__(256) void k_bnapply(const float* __restrict__ H, const int* __restrict__ y,
        const float* __restrict__ bnsum, const int* __restrict__ dcnt,
        const float* __restrict__ gamma, const float* __restrict__ beta,
        ushortT* __restrict__ Hbf){
  int idx = blockIdx.x*256 + threadIdx.x;
  if (idx < NN*HIDC) d_bnapply(idx, H, y, bnsum, dcnt, gamma, beta, Hbf);
}

// ---- FUSED: block0 = trinv (proven); blocks 1..128 = bnpart(h1) ----
__global__ __launch_bounds__(256) void k_trinv_bn(const double* __restrict__ L,
      const double* __restrict__ sdd, double* __restrict__ Rinv,
      const float* __restrict__ H, const int* __restrict__ y, float* __restrict__ bnsum){
  int t = threadIdx.x;
  if (blockIdx.x > 0){
    d_bnpart(blockIdx.x - 1, t, H, y, bnsum);
    return;
  }
  __shared__ double gl[64][65];
  __shared__ double Xl[64][65];
  __shared__ double sdinv[64];
  __shared__ double Sl[3][16][17];
  #pragma unroll
  for (int q = 0; q < 16; q++){
    int idx = t + (q << 8);
    gl[idx >> 6][idx & 63] = L[idx];
  }
  if (t < 64) sdinv[t] = sdd[t];
  for (int idx = t; idx < 64*65; idx += 256)
    ((double*)Xl)[idx] = 0.0;
  __syncthreads();
  if (t < 64){
    int b = t >> 4, c2 = t & 15;
    int g0 = b << 4;
    int gc = g0 + c2;
    Xl[gc][gc] = sdinv[gc];
    for (int i = c2 - 1; i >= 0; i--){
      int gi = g0 + i;
      double s = 0.0;
      for (int k2 = i + 1; k2 <= c2; k2++)
        s += gl[g0 + k2][gi] * Xl[g0 + k2][gc];
      Xl[gi][gc] = -s * sdinv[gi];
    }
  }
  __syncthreads();
  for (int d = 1; d < 4; d++){
    int np = 4 - d;
    int tot = np << 8;
    for (int e = t; e < tot; e += 256){
      int p = e >> 8;
      int i = (e >> 4) & 15, jj = e & 15;
      int gi = (p << 4) + i, gj = ((p + d) << 4) + jj;
      double s = 0.0;
      int a0 = (p + 1) << 4, a1 = (p + d + 1) << 4;
      for (int a = a0; a < a1; a++)
        s += gl[a][gi] * Xl[a][gj];
      Sl[p][i][jj] = s;
    }
    __syncthreads();
    for (int e = t; e < tot; e += 256){
      int p = e >> 8;
      int i = (e >> 4) & 15, jj = e & 15;
      int gi = (p << 4) + i, gj = ((p + d) << 4) + jj;
      double s = 0.0;
      #pragma unroll
      for (int k2 = 0; k2 < 16; k2++)
        s += Xl[gi][(p << 4) + k2] * Sl[p][k2][jj];
      Xl[gi][gj] = -s;
    }
    __syncthreads();
  }
  #pragma unroll
  for (int q = 0; q < 16; q++){
    int e2 = t + (q << 8);
    Rinv[e2] = Xl[e2 >> 6][e2 & 63];
  }
}

// ---- FUSED: blocks [0,1024) = applyR (+f32 Qb out); rest = bnapply(h1) ----
__global__ __launch_bounds__(256) void k_applyR_bn(const double* __restrict__ srcQ,
      const double* __restrict__ Rinv, double* __restrict__ dst, float* __restrict__ Bf1,
      const float* __restrict__ H, const int* __restrict__ y,
      const float* __restrict__ bnsum, const int* __restrict__ dcnt,
      const float* __restrict__ gamma, const float* __restrict__ beta,
      ushortT* __restrict__ Hbf){
  int t = threadIdx.x;
  if (blockIdx.x >= NN/4){
    int idx = (blockIdx.x - NN/4)*256 + t;
    if (idx < NN*HIDC) d_bnapply(idx, H, y, bnsum, dcnt, gamma, beta, Hbf);
    return;
  }
  __shared__ double Rs[64][65];
  #pragma unroll
  for (int q = 0; q < 16; q++){
    int idx = t + q*256;
    Rs[idx >> 6][idx & 63] = Rinv[idx];
  }
  __syncthreads();
  int r = blockIdx.x*4 + (t >> 6);
  int j = t & 63;
  const double* rowp = srcQ + (size_t)r*RK;
  double s = 0.0;
  for (int k = 0; k <= j; k++) s += rowp[k] * Rs[k][j];
  dst[(size_t)r*RK + j] = s;
  Bf1[(size_t)r*RK + j] = (float)s;
}

// ---- FUSED: [0,64) qsum | [64,64+1024) spmmC-f32 | rest gemm_hw2(h1) ----
__global__ __launch_bounds__(256) void k_qsum_spmmC_hw2(
    const double* __restrict__ Q, double* __restrict__ qs,
    const int* __restrict__ ptr, const int* __restrict__ src, const float* __restrict__ cf,
    const float* __restrict__ Xf, float* __restrict__ Cm,
    const ushortT* __restrict__ A, const ushortT* __restrict__ Bm,
    const ushortT* __restrict__ Bl, float* __restrict__ Ca, float* __restrict__ Cb){
  int t = threadIdx.x;
  if (blockIdx.x < 64){
    int j = blockIdx.x;
    double a = 0.0;
    for (int n = t; n < NN; n += 256) a += Q[(size_t)n*RK + j];
    __shared__ double sh[256];
    sh[t] = a; __syncthreads();
    for (int off = 128; off > 0; off >>= 1){ if (t < off) sh[t] += sh[t+off]; __syncthreads(); }
    if (t == 0) qs[j] = sh[0];
    return;
  }
  if (blockIdx.x < 64 + NN/4){
    int seg = (blockIdx.x - 64)*4 + (t >> 6);
    int lane = t & 63;
    double acc = 0.0;
    int p0 = ptr[seg], p1 = ptr[seg+1];
    for (int p = p0; p < p1; ++p){
      acc += (double)cf[p] * (double)Xf[(size_t)src[p]*RK + lane];
    }
    Cm[(size_t)seg*RK + lane] = (float)acc;
    return;
  }
  d_hw2(blockIdx.x - 64 - NN/4, t, A, Bm, Bl, Ca, Cb);
}

// ---- FUSED: [0,128) fin-chores (deg2 + zero Tm/Umu/bnsum) | rest spmm2 ----
__global__ void k_fin_spmm2(
    const float* __restrict__ Cm, const double* __restrict__ qs, float* __restrict__ dinv2,
    float* __restrict__ Tm, float* __restrict__ Um, float* __restrict__ bnsum,
    const int* __restrict__ ptr, const int* __restrict__ src, const float* __restrict__ cf,
    const float* __restrict__ Xa, const float* __restrict__ Xb2,
    float* __restrict__ zout, const float* __restrict__ self_dinv,
    const float* __restrict__ bmu, const float* __restrict__ blv){
  int t = threadIdx.x;
  if (blockIdx.x < 128){
    int idx = blockIdx.x*256 + t;    // < 32768 = RK*HIDC
    Tm[idx] = 0.f;
    if (idx < 2*RK*RK) Um[idx] = 0.f;
    if (idx < 8*HIDC)  bnsum[idx] = 0.f;
    if (idx < NN){
      double s = 0.0;
      #pragma unroll
      for (int k = 0; k < RK; k++) s += (double)Cm[(size_t)idx*RK + k] * qs[k];
      dinv2[idx] = (s > 0.0) ? (float)(1.0/sqrt(s)) : 0.f;
    }
    return;
  }
  int bb = blockIdx.x - 128;         // 0 .. 2*NN/4-1
  int second = bb >= NN/4;
  int seg = (second ? bb - NN/4 : bb)*4 + (t >> 6);
  int lane = t & 63;
  const float* X = second ? Xb2 : Xa;
  const float* bias = second ? blv : bmu;
  float* Y = zout + (second ? (size_t)NN*OUTC : 0);
  float acc0;
  {
    float sd = self_dinv[seg];
    acc0 = sd*sd * X[(size_t)seg*OUTC + lane];
  }
  int p0 = ptr[seg], p1 = ptr[seg+1];
  for (int p = p0; p < p1; ++p){
    acc0 += cf[p] * X[(size_t)src[p]*OUTC + lane];
  }
  acc0 += bias[lane];
  Y[(size_t)seg*OUTC + lane] = acc0;
}

// ---------------- launch ----------------
extern "C" void kernel_launch(void* const* d_in, const int* in_sizes, int n_in,
                              void* d_out, int out_size, void* d_ws, size_t ws_size,
                              hipStream_t stream){
  (void)in_sizes; (void)n_in; (void)out_size;
  const void* x_in  = d_in[0];
  const int*  ei    = (const int*)d_in[1];
  const void* w_in  = d_in[2];
  const int*  yv    = (const int*)d_in[3];
  const void* W1i   = d_in[4];
  const void* b1i   = d_in[5];
  const void* Wmui  = d_in[6];
  const void* bmui  = d_in[7];
  const void* Wlvi  = d_in[8];
  const void* blvi  = d_in[9];
  const void* gmi   = d_in[10];
  const void* bti   = d_in[11];
  const int* rowA = ei;
  const int* colA = ei + NEDG;
  float* zout = (float*)d_out;

  // ---- workspace ----
  double* Dp = (double*)d_ws;
  size_t od = 0;
  double* Qd0 = Dp + od; od += (size_t)NN*RK;
  double* Qd1 = Dp + od; od += (size_t)NN*RK;
  double* Gd  = Dp + od; od += RK*RK;
  double* Rid = Dp + od; od += RK*RK;
  double* qsd = Dp + od; od += RK;
  double* sdd = Dp + od; od += RK;
  float* Fp = (float*)(Dp + od);
  size_t o = 0;
  float* xf   = Fp + o; o += (size_t)NN*INC;       // reused as h1/h2 buffer
  float* W1f  = Fp + o; o += (size_t)INC*HIDC;
  float* b1f  = Fp + o; o += HIDC;
  float* Wmuf = Fp + o; o += (size_t)HIDC*OUTC;
  float* bmuf = Fp + o; o += OUTC;
  float* Wlvf = Fp + o; o += (size_t)HIDC*OUTC;
  float* blvf = Fp + o; o += OUTC;
  float* gmf  = Fp + o; o += NDOM*HIDC;
  float* btf  = Fp + o; o += NDOM*HIDC;
  float* wf   = Fp + o; o += NEDG;
  float* hwA  = Fp + o; o += (size_t)NN*OUTC;
  float* hwB  = Fp + o; o += (size_t)NN*OUTC;
  float* Bf1  = Fp + o; o += (size_t)NN*RK;
  float* Cm   = Fp + o; o += (size_t)NN*RK;
  float* Qf0  = Fp + o; o += (size_t)NN*RK;
  float* Qf1  = Fp + o; o += (size_t)NN*RK;
  float* Tm   = Fp + o; o += (size_t)RK*HIDC;
  float* Umu  = Fp + o; o += 2*RK*RK;
  float* deg1 = Fp + o; o += NN;
  float* dinv1= Fp + o; o += NN;
  float* dinv2= Fp + o; o += NN;
  float* norm1= Fp + o; o += NEDG;
  float* bnsum= Fp + o; o += 8*HIDC;
  float* csrW = Fp + o; o += NEDG;
  float* cscW = Fp + o; o += NEDG;
  float* cscN = Fp + o; o += NEDG;
  ushortT* xbf   = (ushortT*)(Fp + o); o += (size_t)NN*INC/2;
  ushortT* W1bf  = (ushortT*)(Fp + o); o += (size_t)INC*HIDC/2;
  ushortT* xw1bf = (ushortT*)(Fp + o); o += (size_t)NN*HIDC/2;
  ushortT* hbf   = (ushortT*)(Fp + o); o += (size_t)NN*HIDC/2;
  ushortT* Wmubf = (ushortT*)(Fp + o); o += (size_t)HIDC*OUTC/2;
  ushortT* Wlvbf = (ushortT*)(Fp + o); o += (size_t)HIDC*OUTC/2;
  int* Ip = (int*)(Fp + o);
  size_t oi = 0;
  int* cntR = Ip + oi; oi += NN;
  int* ptrR = Ip + oi; oi += NN + 1;
  int* posR = Ip + oi; oi += NN;
  int* eidR = Ip + oi; oi += NEDG;
  int* cntC = Ip + oi; oi += NN;
  int* ptrC = Ip + oi; oi += NN + 1;
  int* posC = Ip + oi; oi += NN;
  int* eidC = Ip + oi; oi += NEDG;
  int* csrSrc = Ip + oi; oi += NEDG;
  int* cscSrc = Ip + oi; oi += NEDG;
  int* dcnt = Ip + oi; oi += NDOM;
  int* dflag= Ip + oi; oi += 1;

  size_t need = od*sizeof(double) + o*sizeof(float) + (oi+16)*sizeof(int);
  if (ws_size < need) return;

  float* hbuf = xf;  // x dead after xw1 GEMM

  const int T = 256;
  k_detect<<<1,T,0,stream>>>((const unsigned short*)x_in, dflag);
  k_upcast_all<<<cdiv(OFFT,T),T,0,stream>>>(
      x_in, W1i, w_in, Wmui, Wlvi, gmi, bti, b1i, bmui, blvi, dflag,
      xf, W1f, wf, Wmuf, Wlvf, gmf, btf, b1f, bmuf, blvf,
      xbf, W1bf, Wmubf, Wlvbf);

  k_prep<<<cdiv(NN,T),T,0,stream>>>(deg1, cntR, cntC, dcnt, bnsum);
  k_hist <<<cdiv(NEDG,T),T,0,stream>>>(rowA, colA, wf, deg1, cntR, cntC);
  k_dinv <<<cdiv(NN,T),T,0,stream>>>(deg1, dinv1, NN);
  k_norm1<<<cdiv(NEDG,T),T,0,stream>>>(rowA, colA, wf, dinv1, norm1);
  k_scan4096<<<1,1024,0,stream>>>(cntR, ptrR, posR);
  k_scan4096<<<1,1024,0,stream>>>(cntC, ptrC, posC);
  k_scatter<<<cdiv(NEDG,T),T,0,stream>>>(rowA, colA, posR, posC, eidR, eidC);
  k_edges<<<cdiv(NEDG,T),T,0,stream>>>(rowA, colA, wf, norm1, eidR, eidC,
                                       csrSrc, csrW, cscSrc, cscW, cscN);
  k_omega<<<cdiv(NN*RK,T),T,0,stream>>>(Qf0, Gd);  // f32 seed + Gd zero
  k_dcnt <<<cdiv(NN,T),T,0,stream>>>(yv, dcnt);

  // ---- branch-1 head (bf16-only xw1) ----
  k_gemm_bf16<<<dim3(HIDC/64, NN/64),256,0,stream>>>(xbf, W1bf, xw1bf);

  // ---- branch-2 subspace chain up to Gram (64-thread blocks, r25-proven) ----
  k_spmm32<<<NN,64,0,stream>>>(ptrR, csrSrc, csrW, Qf0, Qf1);       // P1
  k_spmm32<<<NN,64,0,stream>>>(ptrC, cscSrc, cscW, Qf1, Qf0);       // P2
  k_spmm32<<<NN,64,0,stream>>>(ptrR, csrSrc, csrW, Qf0, Qf1);       // P3
  k_spmm32<<<NN,64,0,stream>>>(ptrC, cscSrc, cscW, Qf1, Qf0);       // P4
  k_spmm32to64<<<NN,64,0,stream>>>(ptrR, csrSrc, csrW, Qf0, Qd1);   // P5 (f64)
  k_gram64<<<NN/64,256,0,stream>>>(Qd1, Gd);

  // ---- FUSED: chol | h1 spmm ----
  k_chol_spmm<<<NN+1,256,0,stream>>>(Gd, sdd, ptrC, cscSrc, cscN, xw1bf, hbuf,
                                     dinv1, b1f);
  // ---- FUSED: trinv | bnpart(h1) ----
  k_trinv_bn<<<1+NN/32,256,0,stream>>>(Gd, sdd, Rid, hbuf, yv, bnsum);
  // ---- FUSED: applyR (+Bf1) | bnapply(h1) ----
  k_applyR_bn<<<NN/4 + cdiv(NN*HIDC,T),256,0,stream>>>(Qd1, Rid, Qd0, Bf1,
      hbuf, yv, bnsum, dcnt, gmf, btf, hbf);
  // ---- FUSED: qsum | spmmC-f32 | gemm_hw2(h1) ----
  k_qsum_spmmC_hw2<<<64 + NN/4 + 2*(NN/64),256,0,stream>>>(Qd0, qsd,
      ptrC, cscSrc, cscW, Bf1, Cm, hbf, Wmubf, Wlvbf, hwA, hwB);
  // ---- FUSED: fin-chores | output spmm2(h1) ----
  k_fin_spmm2<<<128 + 2*(NN/4),256,0,stream>>>(Cm, qsd, dinv2, Tm, Umu, bnsum,
      ptrC, cscSrc, cscN, hwA, hwB, zout, dinv1, bmuf, blvf);

  // ---- branch-2 tail ----
  k_gemm_tn_bfm<<<dim3(HIDC/64, 8),256,0,stream>>>(Bf1, dinv2, xw1bf, Tm);
  k_gemm_nn<<<dim3(HIDC/64, NN/64),256,0,stream>>>(NN,HIDC,RK, Cm,RK, Tm,HIDC, hbuf,HIDC, dinv2, nullptr, b1f);
  k_bnpart<<<NN/32,256,0,stream>>>(hbuf, yv, bnsum);
  k_bnapply<<<cdiv(NN*HIDC,T),T,0,stream>>>(hbuf, yv, bnsum, dcnt, gmf, btf, hbf);
  k_gemm_hw2<<<2*(NN/64),256,0,stream>>>(hbf, Wmubf, Wlvbf, hwA, hwB);
  k_gemm_tn_sk2<<<dim3(RK/16, RK/16, 32),256,0,stream>>>(Bf1, hwA, hwB, Umu, dinv2);
  k_gemm_nn2<<<dim3(1, NN/64, 2),256,0,stream>>>(Cm, Umu, dinv2, bmuf, blvf, zout);
}